// Round 15
// baseline (313.897 us; speedup 1.0000x reference)
//
#include <hip/hip_runtime.h>

#define NN 100000
#define NE 1600000
#define NSB 391  // ceil(NN/256) scan blocks

#define LOG2E 1.4426950408889634f
#define LN2 0.6931471805599453f

typedef short short4v __attribute__((ext_vector_type(4)));
typedef short short8v __attribute__((ext_vector_type(8)));
typedef float f32x2 __attribute__((ext_vector_type(2)));
typedef float f32x4 __attribute__((ext_vector_type(4)));
typedef unsigned u32x4 __attribute__((ext_vector_type(4)));

static __device__ __forceinline__ unsigned f2bf(float x) {
    unsigned b = __float_as_uint(x);
    return (b + 0x7FFFu + ((b >> 16) & 1u)) >> 16;  // RNE bf16 bits
}
static __device__ __forceinline__ float bflo(unsigned u) { return __uint_as_float(u << 16); }
static __device__ __forceinline__ float bfhi(unsigned u) { return __uint_as_float(u & 0xFFFF0000u); }
static __device__ __forceinline__ int imin(int a, int b) { return a < b ? a : b; }
static __device__ __forceinline__ short8v mk8(short4v a, short4v b) {
    short8v r;
    r[0] = a[0]; r[1] = a[1]; r[2] = a[2]; r[3] = a[3];
    r[4] = b[0]; r[5] = b[1]; r[6] = b[2]; r[7] = b[3];
    return r;
}

// Swizzled LDS tile address (shorts): [32][64] tile, 16B blocks XOR'd by row&7.
static __device__ __forceinline__ int swz(int row, int colblk) {
    return row * 64 + ((colblk ^ (row & 7)) << 3);
}

// Build one A fragment (16 shorts logical cols of a row).
static __device__ __forceinline__ void frag_reads(const short* xl, int row, int g,
                                                  short8v& a0, short8v& a1) {
    const int sub = (g & 1) * 4;
    const int cb = g >> 1;
    const short4v p0 = *(const short4v*)&xl[swz(row, cb + 0) + sub];
    const short4v p1 = *(const short4v*)&xl[swz(row, cb + 2) + sub];
    const short4v p2 = *(const short4v*)&xl[swz(row, cb + 4) + sub];
    const short4v p3 = *(const short4v*)&xl[swz(row, cb + 6) + sub];
    a0 = mk8(p0, p1);
    a1 = mk8(p2, p3);
}

// One edge's gated-message contribution. ps is an fp8-e4m3 pair (f,s).
static __device__ __forceinline__ float edge_acc(uint4 m, unsigned ps, f32x2 pd2,
                                                 const f32x2* __restrict__ w2, float acc) {
    f32x2 z = __builtin_amdgcn_cvt_pk_f32_fp8((int)ps, false);
    z += pd2;
    const float e50 = bflo(m.y), e51 = bfhi(m.y);
    const float e52 = bflo(m.z), e53 = bfhi(m.z);
    const float e54 = bflo(m.w);
    z += e50 * w2[0];
    z += e51 * w2[1];
    z += e52 * w2[2];
    z += e53 * w2[3];
    z += e54 * w2[4];
    const float sig = __builtin_amdgcn_rcpf(1.f + __builtin_amdgcn_exp2f(z.x));
    const float gg = __builtin_amdgcn_logf(1.f + __builtin_amdgcn_exp2f(z.y));
    return fmaf(sig, gg, acc);
}

// ---------------------------------------------------------------------------
// Pack into MFMA B-fragment layout (2 conv layers x 4 mats + lin0).
__global__ __launch_bounds__(256) void k_wpack(const float* __restrict__ cfw,
                                               const float* __restrict__ csw,
                                               const float* __restrict__ l0w,
                                               unsigned short* __restrict__ Bp) {
    const int qq = blockIdx.x * 256 + threadIdx.x;  // 4608 total
    const float* src;
    float scale;
    int roff, ct, kh, l;
    if (qq < 4096) {
        const int layer = qq >> 11;
        const int q = qq & 2047;
        const int m = q >> 9;
        const int rem = q & 511;
        ct = rem >> 7;
        kh = (rem >> 6) & 1;
        l = rem & 63;
        scale = (m & 1) ? LOG2E : -LOG2E;
        src = ((m & 1) ? csw : cfw) + (size_t)layer * 133 * 64;
        roff = (m >> 1) ? 64 : 0;
    } else {
        const int p = qq - 4096;
        ct = p >> 7;
        kh = (p >> 6) & 1;
        l = p & 63;
        scale = 1.f;
        src = l0w;
        roff = 0;
    }
    const int n = ct * 16 + (l & 15);
#pragma unroll
    for (int j = 0; j < 8; j++) {
        const int k = kh * 32 + ((j < 4) ? (4 * (l >> 4) + j) : (16 + 4 * (l >> 4) + j - 4));
        Bp[(size_t)qq * 8 + j] = (unsigned short)f2bf(scale * src[(size_t)(roff + k) * 64 + n]);
    }
}

// ---------------------------------------------------------------------------
// Fused, mod-7 interleaved (4375 = 625*7):
//   blockIdx%7 < 2 : dst histogram + per-edge rank (latency role)
//   else           : XB = bf16(relu(h @ lin0_w + b)) via MFMA (compute role)
__global__ __launch_bounds__(256) void k_lin0m_hist(const float* __restrict__ h,
                                                    const unsigned short* __restrict__ Bp0,
                                                    const float* __restrict__ b,
                                                    unsigned short* __restrict__ xb,
                                                    const int* __restrict__ ei,
                                                    int* __restrict__ cnt,
                                                    int* __restrict__ rank) {
    __shared__ __align__(16) short xl[32 * 64];
    const int r7 = blockIdx.x % 7;
    const int q7 = blockIdx.x / 7;
    if (r7 < 2) {
        const int base = (q7 * 2 + r7) * 1280 + threadIdx.x;
        int r[5];
#pragma unroll
        for (int j = 0; j < 5; j++) r[j] = atomicAdd(&cnt[ei[NE + base + j * 256]], 1);
#pragma unroll
        for (int j = 0; j < 5; j++) rank[base + j * 256] = r[j];
        return;
    }
    const int rowbase = (q7 * 5 + (r7 - 2)) * 32;
    {
        const float4* hs = (const float4*)(h + (size_t)rowbase * 64);
#pragma unroll
        for (int it = 0; it < 2; it++) {
            const int i = threadIdx.x + it * 256;
            const float4 v = hs[i];
            short4v sv;
            sv[0] = (short)f2bf(v.x);
            sv[1] = (short)f2bf(v.y);
            sv[2] = (short)f2bf(v.z);
            sv[3] = (short)f2bf(v.w);
            const int row = i >> 4;
            *(short4v*)&xl[swz(row, (i >> 1) & 7) + (i & 1) * 4] = sv;
        }
    }
    __syncthreads();
    const int ct = threadIdx.x >> 6;
    const int l = threadIdx.x & 63;
    const int lm = l & 15;
    const int g = l >> 4;
    short8v A[2][2];
#pragma unroll
    for (int rt = 0; rt < 2; rt++) frag_reads(xl, rt * 16 + lm, g, A[rt][0], A[rt][1]);
    const short* bp = (const short*)Bp0;
    const short8v B0 = *(const short8v*)&bp[((ct * 2 + 0) * 64 + l) * 8];
    const short8v B1 = *(const short8v*)&bp[((ct * 2 + 1) * 64 + l) * 8];
    const int col = ct * 16 + lm;
    const float bc = b[col];
#pragma unroll
    for (int rt = 0; rt < 2; rt++) {
        f32x4 a = {0.f, 0.f, 0.f, 0.f};
        a = __builtin_amdgcn_mfma_f32_16x16x32_bf16(A[rt][0], B0, a, 0, 0, 0);
        a = __builtin_amdgcn_mfma_f32_16x16x32_bf16(A[rt][1], B1, a, 0, 0, 0);
#pragma unroll
        for (int reg = 0; reg < 4; reg++) {
            const int rowg = rowbase + rt * 16 + g * 4 + reg;
            xb[(size_t)rowg * 64 + col] = (unsigned short)f2bf(fmaxf(a[reg] + bc, 0.f));
        }
    }
}

// ---------------------------------------------------------------------------
__global__ __launch_bounds__(256) void k_scan1(const int* __restrict__ cnt,
                                               int* __restrict__ offs, int* __restrict__ bsum) {
    __shared__ int sm[256];
    const int t = threadIdx.x;
    const int i = blockIdx.x * 256 + t;
    const int v = (i < NN) ? cnt[i] : 0;
    sm[t] = v;
    __syncthreads();
    for (int off = 1; off < 256; off <<= 1) {
        const int x = (t >= off) ? sm[t - off] : 0;
        __syncthreads();
        sm[t] += x;
        __syncthreads();
    }
    if (i < NN) offs[i] = sm[t] - v;
    if (t == 255) bsum[blockIdx.x] = sm[255];
}

__global__ __launch_bounds__(512) void k_scan2(int* __restrict__ bsum) {
    __shared__ int sm[512];
    const int t = threadIdx.x;
    const int v = (t < NSB) ? bsum[t] : 0;
    sm[t] = v;
    __syncthreads();
    for (int off = 1; off < 512; off <<= 1) {
        const int x = (t >= off) ? sm[t - off] : 0;
        __syncthreads();
        sm[t] += x;
        __syncthreads();
    }
    if (t < NSB) bsum[t] = sm[t] - v;
}

__global__ __launch_bounds__(256) void k_scan3(int* __restrict__ offs,
                                               const int* __restrict__ bsum) {
    const int i = blockIdx.x * 256 + threadIdx.x;
    if (i < NN) offs[i] += bsum[blockIdx.x];
    if (i == 0) offs[NN] = NE;
}

// ---------------------------------------------------------------------------
// Fused, mod-7 interleaved: scatter (latency role) / MFMA proj layer 0.
__global__ __launch_bounds__(256) void k_scat_proj(const int* __restrict__ ei,
                                                   const float* __restrict__ eattr,
                                                   const float* __restrict__ sw,
                                                   const float* __restrict__ sb,
                                                   const int* __restrict__ rank,
                                                   const int* __restrict__ offs,
                                                   unsigned* __restrict__ meta,
                                                   const unsigned short* __restrict__ xb,
                                                   const unsigned short* __restrict__ Bp,
                                                   const float* __restrict__ bfv,
                                                   const float* __restrict__ bsv,
                                                   unsigned* __restrict__ Pd,
                                                   unsigned short* __restrict__ Ps8) {
    __shared__ __align__(16) short xl[32 * 64];
    const int r7 = blockIdx.x % 7;
    const int q7 = blockIdx.x / 7;
    if (r7 < 2) {
        __shared__ float swl[25], sbl[5];
        if (threadIdx.x < 25) swl[threadIdx.x] = sw[threadIdx.x];
        if (threadIdx.x >= 32 && threadIdx.x < 37) sbl[threadIdx.x - 32] = sb[threadIdx.x - 32];
        __syncthreads();
        const int base = (q7 * 2 + r7) * 1280 + threadIdx.x;
        int s[5], d[5], r[5];
        float ea[5][5];
#pragma unroll
        for (int j = 0; j < 5; j++) {
            const int e = base + j * 256;
            s[j] = ei[e];
            d[j] = ei[NE + e];
            r[j] = rank[e];
#pragma unroll
            for (int k = 0; k < 5; k++) ea[j][k] = eattr[(size_t)e * 5 + k];
        }
        int pos[5];
#pragma unroll
        for (int j = 0; j < 5; j++) pos[j] = offs[d[j]] + r[j];  // random load, no RMW
#pragma unroll
        for (int j = 0; j < 5; j++) {
            unsigned u5[5];
#pragma unroll
            for (int k = 0; k < 5; k++) {
                float a = sbl[k];
#pragma unroll
                for (int q = 0; q < 5; q++) a += ea[j][q] * swl[q * 5 + k];
                u5[k] = f2bf(fmaxf(a, 0.f));
            }
            u32x4 m;
            m[0] = (unsigned)s[j];
            m[1] = u5[0] | (u5[1] << 16);
            m[2] = u5[2] | (u5[3] << 16);
            m[3] = u5[4];
            __builtin_nontemporal_store(m, (u32x4*)&meta[(size_t)pos[j] * 4]);
        }
        return;
    }
    // ---- projm path (layer 0) ----
    const int rowbase = (q7 * 5 + (r7 - 2)) * 32;
    {
        const u32x4* xsrc = (const u32x4*)(xb + (size_t)rowbase * 64);
        const int i = threadIdx.x;
        const u32x4 v = __builtin_nontemporal_load(&xsrc[i]);
        *(u32x4*)&xl[swz(i >> 3, i & 7)] = v;
    }
    __syncthreads();
    const int ct = threadIdx.x >> 6;
    const int l = threadIdx.x & 63;
    const int lm = l & 15;
    const int g = l >> 4;
    short8v A[2][2];
#pragma unroll
    for (int rt = 0; rt < 2; rt++) frag_reads(xl, rt * 16 + lm, g, A[rt][0], A[rt][1]);
    const short* bp = (const short*)Bp;
    f32x4 acc[4][2];
#pragma unroll
    for (int m = 0; m < 4; m++) {
        const short8v B0 = *(const short8v*)&bp[(((m * 4 + ct) * 2 + 0) * 64 + l) * 8];
        const short8v B1 = *(const short8v*)&bp[(((m * 4 + ct) * 2 + 1) * 64 + l) * 8];
#pragma unroll
        for (int rt = 0; rt < 2; rt++) {
            f32x4 a = {0.f, 0.f, 0.f, 0.f};
            a = __builtin_amdgcn_mfma_f32_16x16x32_bf16(A[rt][0], B0, a, 0, 0, 0);
            a = __builtin_amdgcn_mfma_f32_16x16x32_bf16(A[rt][1], B1, a, 0, 0, 0);
            acc[m][rt] = a;
        }
    }
    const int col = ct * 16 + lm;
    const float bfb = -LOG2E * bfv[col];
    const float bsb = LOG2E * bsv[col];
#pragma unroll
    for (int rt = 0; rt < 2; rt++) {
#pragma unroll
        for (int reg = 0; reg < 4; reg++) {
            const int rowg = rowbase + rt * 16 + g * 4 + reg;
            Pd[(size_t)rowg * 64 + col] =
                f2bf(acc[0][rt][reg] + bfb) | (f2bf(acc[1][rt][reg] + bsb) << 16);
            Ps8[(size_t)rowg * 64 + col] = (unsigned short)__builtin_amdgcn_cvt_pk_fp8_f32(
                acc[2][rt][reg], acc[3][rt][reg], 0, false);
        }
    }
}

// ---------------------------------------------------------------------------
// MFMA projections (standalone, layer 1), 32 rows per block, swizzled LDS.
__global__ __launch_bounds__(256) void k_projm(const unsigned short* __restrict__ xb,
                                               const unsigned short* __restrict__ Bp,
                                               const float* __restrict__ bfv,
                                               const float* __restrict__ bsv,
                                               unsigned* __restrict__ Pd,
                                               unsigned short* __restrict__ Ps8) {
    __shared__ __align__(16) short xl[32 * 64];
    const int rowbase = blockIdx.x * 32;
    {
        const u32x4* xsrc = (const u32x4*)(xb + (size_t)rowbase * 64);
        const int i = threadIdx.x;
        const u32x4 v = __builtin_nontemporal_load(&xsrc[i]);
        *(u32x4*)&xl[swz(i >> 3, i & 7)] = v;
    }
    __syncthreads();
    const int ct = threadIdx.x >> 6;
    const int l = threadIdx.x & 63;
    const int lm = l & 15;
    const int g = l >> 4;
    short8v A[2][2];
#pragma unroll
    for (int rt = 0; rt < 2; rt++) frag_reads(xl, rt * 16 + lm, g, A[rt][0], A[rt][1]);
    const short* bp = (const short*)Bp;
    f32x4 acc[4][2];
#pragma unroll
    for (int m = 0; m < 4; m++) {
        const short8v B0 = *(const short8v*)&bp[(((m * 4 + ct) * 2 + 0) * 64 + l) * 8];
        const short8v B1 = *(const short8v*)&bp[(((m * 4 + ct) * 2 + 1) * 64 + l) * 8];
#pragma unroll
        for (int rt = 0; rt < 2; rt++) {
            f32x4 a = {0.f, 0.f, 0.f, 0.f};
            a = __builtin_amdgcn_mfma_f32_16x16x32_bf16(A[rt][0], B0, a, 0, 0, 0);
            a = __builtin_amdgcn_mfma_f32_16x16x32_bf16(A[rt][1], B1, a, 0, 0, 0);
            acc[m][rt] = a;
        }
    }
    const int col = ct * 16 + lm;
    const float bfb = -LOG2E * bfv[col];
    const float bsb = LOG2E * bsv[col];
#pragma unroll
    for (int rt = 0; rt < 2; rt++) {
#pragma unroll
        for (int reg = 0; reg < 4; reg++) {
            const int rowg = rowbase + rt * 16 + g * 4 + reg;
            Pd[(size_t)rowg * 64 + col] =
                f2bf(acc[0][rt][reg] + bfb) | (f2bf(acc[1][rt][reg] + bsb) << 16);
            Ps8[(size_t)rowg * 64 + col] = (unsigned short)__builtin_amdgcn_cvt_pk_fp8_f32(
                acc[2][rt][reg], acc[3][rt][reg], 0, false);
        }
    }
}

// ---------------------------------------------------------------------------
// Segment aggregation: 128-thread blocks = 2 independent waves = 2 nodes
// (no barrier; 2 waves/WG doubles waves per workgroup slot -> higher occ).
// Node features bf16 (XB); layer 0 updates XB IN PLACE, layer 1 writes f32 out.
__global__ __launch_bounds__(128) void k_seg(const int* __restrict__ offs,
                                             const uint4* __restrict__ meta,
                                             const unsigned* __restrict__ Pd,
                                             const unsigned short* __restrict__ Ps8,
                                             const float* __restrict__ wfE,
                                             const float* __restrict__ wsE,
                                             const unsigned short* __restrict__ xbin,
                                             float* __restrict__ outf,
                                             unsigned short* __restrict__ xbout) {
    const int n = blockIdx.x * 2 + (threadIdx.x >> 6);
    const int lane = threadIdx.x & 63;
    const int start = __builtin_amdgcn_readfirstlane(offs[n]);
    const int end = __builtin_amdgcn_readfirstlane(offs[n + 1]);
    const unsigned pd = __builtin_nontemporal_load(&Pd[(size_t)n * 64 + lane]);
    f32x2 pd2;
    pd2.x = bflo(pd);
    pd2.y = bfhi(pd);
    f32x2 w2[5];
#pragma unroll
    for (int k = 0; k < 5; k++) {
        f32x2 p;
        p.x = -LOG2E * wfE[k * 64 + lane];
        p.y = LOG2E * wsE[k * 64 + lane];
        w2[k] = p;
    }
    const float xv = bflo((unsigned)xbin[(size_t)n * 64 + lane]);
    float acc = 0.f;
    const int cnt = end - start;
    if (cnt > 0) {
        const int last = end - 1;
        const int nbF = (cnt + 3) >> 2;
        uint4 M0[4], M1[4];
        unsigned PS0[4];
#pragma unroll
        for (int j = 0; j < 4; j++) M0[j] = meta[imin(start + j, last)];
#pragma unroll
        for (int j = 0; j < 4; j++) M1[j] = meta[imin(start + 4 + j, last)];
#pragma unroll
        for (int j = 0; j < 4; j++) PS0[j] = Ps8[(size_t)M0[j].x * 64 + lane];
        for (int b = 0; b < nbF - 1; b++) {
            const int base2 = __builtin_amdgcn_readfirstlane(start + (b + 2) * 4);
            uint4 M2[4];
            unsigned PS1[4];
#pragma unroll
            for (int j = 0; j < 4; j++) M2[j] = meta[imin(base2 + j, last)];
#pragma unroll
            for (int j = 0; j < 4; j++) PS1[j] = Ps8[(size_t)M1[j].x * 64 + lane];
#pragma unroll
            for (int j = 0; j < 4; j++) acc = edge_acc(M0[j], PS0[j], pd2, w2, acc);
#pragma unroll
            for (int j = 0; j < 4; j++) {
                M0[j] = M1[j];
                M1[j] = M2[j];
                PS0[j] = PS1[j];
            }
        }
        const int lb = start + (nbF - 1) * 4;
#pragma unroll
        for (int j = 0; j < 4; j++)
            if (lb + j < end) acc = edge_acc(M0[j], PS0[j], pd2, w2, acc);
    }
    const float res = fmaxf(fmaf(acc, LN2, xv), 0.f);
    if (outf) {
        __builtin_nontemporal_store(res, &outf[(size_t)n * 64 + lane]);  // final f32
    } else {
        xbout[(size_t)n * 64 + lane] = (unsigned short)f2bf(res);  // XB in-place
    }
}

// ---------------------------------------------------------------------------
extern "C" void kernel_launch(void* const* d_in, const int* in_sizes, int n_in,
                              void* d_out, int out_size, void* d_ws, size_t ws_size,
                              hipStream_t stream) {
    const float* h = (const float*)d_in[0];
    const int* ei = (const int*)d_in[1];
    const float* eattr = (const float*)d_in[3];
    const float* lin0_w = (const float*)d_in[5];
    const float* lin0_b = (const float*)d_in[6];
    const float* short_w = (const float*)d_in[7];
    const float* short_b = (const float*)d_in[8];
    const float* conv_f_w = (const float*)d_in[9];
    const float* conv_f_b = (const float*)d_in[10];
    const float* conv_s_w = (const float*)d_in[11];
    const float* conv_s_b = (const float*)d_in[12];

    char* ws = (char*)d_ws;
    uint4* meta = (uint4*)ws;                             // [NE] 16B, 25.6 MB
    unsigned* Pd = (unsigned*)(ws + (size_t)NE * 16);     // [NN*64] u32 (bf16 pair)
    unsigned short* Ps8 = (unsigned short*)(Pd + (size_t)NN * 64);  // [NN*64] u16 (fp8 pair)
    unsigned short* XB = Ps8 + (size_t)NN * 64;           // [NN*64] bf16 node features
    unsigned short* Bp = XB + (size_t)NN * 64;            // [2][16384]+[4096] packed weights
    int* cnt = (int*)(Bp + 36864);                        // [NN]
    int* offs = cnt + NN;                                 // [NN+1]
    int* bsum = offs + NN + 1;                            // [NSB]
    int* rank = bsum + NSB;                               // [NE]

    hipMemsetAsync(cnt, 0, (size_t)NN * 4, stream);
    k_wpack<<<18, 256, 0, stream>>>(conv_f_w, conv_s_w, lin0_w, Bp);
    k_lin0m_hist<<<4375, 256, 0, stream>>>(h, Bp + 32768, lin0_b, XB, ei, cnt, rank);
    k_scan1<<<NSB, 256, 0, stream>>>(cnt, offs, bsum);
    k_scan2<<<1, 512, 0, stream>>>(bsum);
    k_scan3<<<NSB, 256, 0, stream>>>(offs, bsum);
    // layer 0: scatter fused with projm (mod-7 interleaved, overlapped)
    k_scat_proj<<<4375, 256, 0, stream>>>(ei, eattr, short_w, short_b, rank, offs,
                                          (unsigned*)meta, XB, Bp, conv_f_b, conv_s_b,
                                          Pd, Ps8);
    k_seg<<<NN / 2, 128, 0, stream>>>(offs, meta, Pd, Ps8,
                                      conv_f_w + 128 * 64, conv_s_w + 128 * 64,
                                      XB, nullptr, XB);
    // layer 1
    k_projm<<<NN / 32, 256, 0, stream>>>(XB, Bp + 16384, conv_f_b + 64, conv_s_b + 64, Pd, Ps8);
    k_seg<<<NN / 2, 128, 0, stream>>>(offs, meta, Pd, Ps8,
                                      conv_f_w + 133 * 64 + 128 * 64,
                                      conv_s_w + 133 * 64 + 128 * 64,
                                      XB, (float*)d_out, nullptr);
}

// Round 16
// 309.144 us; speedup vs baseline: 1.0154x; 1.0154x over previous
//
#include <hip/hip_runtime.h>

#define NN 100000
#define NE 1600000
#define NSB 391  // ceil(NN/256) scan blocks

#define LOG2E 1.4426950408889634f
#define LN2 0.6931471805599453f

typedef short short4v __attribute__((ext_vector_type(4)));
typedef short short8v __attribute__((ext_vector_type(8)));
typedef float f32x2 __attribute__((ext_vector_type(2)));
typedef float f32x4 __attribute__((ext_vector_type(4)));
typedef unsigned u32x4 __attribute__((ext_vector_type(4)));

static __device__ __forceinline__ unsigned f2bf(float x) {
    unsigned b = __float_as_uint(x);
    return (b + 0x7FFFu + ((b >> 16) & 1u)) >> 16;  // RNE bf16 bits
}
static __device__ __forceinline__ float bflo(unsigned u) { return __uint_as_float(u << 16); }
static __device__ __forceinline__ float bfhi(unsigned u) { return __uint_as_float(u & 0xFFFF0000u); }
static __device__ __forceinline__ int imin(int a, int b) { return a < b ? a : b; }
static __device__ __forceinline__ short8v mk8(short4v a, short4v b) {
    short8v r;
    r[0] = a[0]; r[1] = a[1]; r[2] = a[2]; r[3] = a[3];
    r[4] = b[0]; r[5] = b[1]; r[6] = b[2]; r[7] = b[3];
    return r;
}

// Swizzled LDS tile address (shorts): [32][64] tile, 16B blocks XOR'd by row&7.
static __device__ __forceinline__ int swz(int row, int colblk) {
    return row * 64 + ((colblk ^ (row & 7)) << 3);
}

// Build one A fragment (16 shorts logical cols of a row).
static __device__ __forceinline__ void frag_reads(const short* xl, int row, int g,
                                                  short8v& a0, short8v& a1) {
    const int sub = (g & 1) * 4;
    const int cb = g >> 1;
    const short4v p0 = *(const short4v*)&xl[swz(row, cb + 0) + sub];
    const short4v p1 = *(const short4v*)&xl[swz(row, cb + 2) + sub];
    const short4v p2 = *(const short4v*)&xl[swz(row, cb + 4) + sub];
    const short4v p3 = *(const short4v*)&xl[swz(row, cb + 6) + sub];
    a0 = mk8(p0, p1);
    a1 = mk8(p2, p3);
}

// One edge's gated-message contribution. ps is an fp8-e4m3 pair (f,s).
static __device__ __forceinline__ float edge_acc(uint4 m, unsigned ps, f32x2 pd2,
                                                 const f32x2* __restrict__ w2, float acc) {
    f32x2 z = __builtin_amdgcn_cvt_pk_f32_fp8((int)ps, false);
    z += pd2;
    const float e50 = bflo(m.y), e51 = bfhi(m.y);
    const float e52 = bflo(m.z), e53 = bfhi(m.z);
    const float e54 = bflo(m.w);
    z += e50 * w2[0];
    z += e51 * w2[1];
    z += e52 * w2[2];
    z += e53 * w2[3];
    z += e54 * w2[4];
    const float sig = __builtin_amdgcn_rcpf(1.f + __builtin_amdgcn_exp2f(z.x));
    const float gg = __builtin_amdgcn_logf(1.f + __builtin_amdgcn_exp2f(z.y));
    return fmaf(sig, gg, acc);
}

// ---------------------------------------------------------------------------
// Pack into MFMA B-fragment layout (2 conv layers x 4 mats + lin0).
__global__ __launch_bounds__(256) void k_wpack(const float* __restrict__ cfw,
                                               const float* __restrict__ csw,
                                               const float* __restrict__ l0w,
                                               unsigned short* __restrict__ Bp) {
    const int qq = blockIdx.x * 256 + threadIdx.x;  // 4608 total
    const float* src;
    float scale;
    int roff, ct, kh, l;
    if (qq < 4096) {
        const int layer = qq >> 11;
        const int q = qq & 2047;
        const int m = q >> 9;
        const int rem = q & 511;
        ct = rem >> 7;
        kh = (rem >> 6) & 1;
        l = rem & 63;
        scale = (m & 1) ? LOG2E : -LOG2E;
        src = ((m & 1) ? csw : cfw) + (size_t)layer * 133 * 64;
        roff = (m >> 1) ? 64 : 0;
    } else {
        const int p = qq - 4096;
        ct = p >> 7;
        kh = (p >> 6) & 1;
        l = p & 63;
        scale = 1.f;
        src = l0w;
        roff = 0;
    }
    const int n = ct * 16 + (l & 15);
#pragma unroll
    for (int j = 0; j < 8; j++) {
        const int k = kh * 32 + ((j < 4) ? (4 * (l >> 4) + j) : (16 + 4 * (l >> 4) + j - 4));
        Bp[(size_t)qq * 8 + j] = (unsigned short)f2bf(scale * src[(size_t)(roff + k) * 64 + n]);
    }
}

// ---------------------------------------------------------------------------
// Fused, mod-7 interleaved (4375 = 625*7):
//   blockIdx%7 < 2 : dst histogram + per-edge rank (latency role)
//   else           : XB = bf16(relu(h @ lin0_w + b)) via MFMA (compute role)
__global__ __launch_bounds__(256) void k_lin0m_hist(const float* __restrict__ h,
                                                    const unsigned short* __restrict__ Bp0,
                                                    const float* __restrict__ b,
                                                    unsigned short* __restrict__ xb,
                                                    const int* __restrict__ ei,
                                                    int* __restrict__ cnt,
                                                    int* __restrict__ rank) {
    __shared__ __align__(16) short xl[32 * 64];
    const int r7 = blockIdx.x % 7;
    const int q7 = blockIdx.x / 7;
    if (r7 < 2) {
        const int base = (q7 * 2 + r7) * 1280 + threadIdx.x;
        int r[5];
#pragma unroll
        for (int j = 0; j < 5; j++) r[j] = atomicAdd(&cnt[ei[NE + base + j * 256]], 1);
#pragma unroll
        for (int j = 0; j < 5; j++) rank[base + j * 256] = r[j];
        return;
    }
    const int rowbase = (q7 * 5 + (r7 - 2)) * 32;
    {
        const float4* hs = (const float4*)(h + (size_t)rowbase * 64);
#pragma unroll
        for (int it = 0; it < 2; it++) {
            const int i = threadIdx.x + it * 256;
            const float4 v = hs[i];
            short4v sv;
            sv[0] = (short)f2bf(v.x);
            sv[1] = (short)f2bf(v.y);
            sv[2] = (short)f2bf(v.z);
            sv[3] = (short)f2bf(v.w);
            const int row = i >> 4;
            *(short4v*)&xl[swz(row, (i >> 1) & 7) + (i & 1) * 4] = sv;
        }
    }
    __syncthreads();
    const int ct = threadIdx.x >> 6;
    const int l = threadIdx.x & 63;
    const int lm = l & 15;
    const int g = l >> 4;
    short8v A[2][2];
#pragma unroll
    for (int rt = 0; rt < 2; rt++) frag_reads(xl, rt * 16 + lm, g, A[rt][0], A[rt][1]);
    const short* bp = (const short*)Bp0;
    const short8v B0 = *(const short8v*)&bp[((ct * 2 + 0) * 64 + l) * 8];
    const short8v B1 = *(const short8v*)&bp[((ct * 2 + 1) * 64 + l) * 8];
    const int col = ct * 16 + lm;
    const float bc = b[col];
#pragma unroll
    for (int rt = 0; rt < 2; rt++) {
        f32x4 a = {0.f, 0.f, 0.f, 0.f};
        a = __builtin_amdgcn_mfma_f32_16x16x32_bf16(A[rt][0], B0, a, 0, 0, 0);
        a = __builtin_amdgcn_mfma_f32_16x16x32_bf16(A[rt][1], B1, a, 0, 0, 0);
#pragma unroll
        for (int reg = 0; reg < 4; reg++) {
            const int rowg = rowbase + rt * 16 + g * 4 + reg;
            xb[(size_t)rowg * 64 + col] = (unsigned short)f2bf(fmaxf(a[reg] + bc, 0.f));
        }
    }
}

// ---------------------------------------------------------------------------
__global__ __launch_bounds__(256) void k_scan1(const int* __restrict__ cnt,
                                               int* __restrict__ offs, int* __restrict__ bsum) {
    __shared__ int sm[256];
    const int t = threadIdx.x;
    const int i = blockIdx.x * 256 + t;
    const int v = (i < NN) ? cnt[i] : 0;
    sm[t] = v;
    __syncthreads();
    for (int off = 1; off < 256; off <<= 1) {
        const int x = (t >= off) ? sm[t - off] : 0;
        __syncthreads();
        sm[t] += x;
        __syncthreads();
    }
    if (i < NN) offs[i] = sm[t] - v;
    if (t == 255) bsum[blockIdx.x] = sm[255];
}

__global__ __launch_bounds__(512) void k_scan2(int* __restrict__ bsum) {
    __shared__ int sm[512];
    const int t = threadIdx.x;
    const int v = (t < NSB) ? bsum[t] : 0;
    sm[t] = v;
    __syncthreads();
    for (int off = 1; off < 512; off <<= 1) {
        const int x = (t >= off) ? sm[t - off] : 0;
        __syncthreads();
        sm[t] += x;
        __syncthreads();
    }
    if (t < NSB) bsum[t] = sm[t] - v;
}

__global__ __launch_bounds__(256) void k_scan3(int* __restrict__ offs,
                                               const int* __restrict__ bsum) {
    const int i = blockIdx.x * 256 + threadIdx.x;
    if (i < NN) offs[i] += bsum[blockIdx.x];
    if (i == 0) offs[NN] = NE;
}

// ---------------------------------------------------------------------------
// Fused, mod-7 interleaved: scatter (latency role) / MFMA proj layer 0.
__global__ __launch_bounds__(256) void k_scat_proj(const int* __restrict__ ei,
                                                   const float* __restrict__ eattr,
                                                   const float* __restrict__ sw,
                                                   const float* __restrict__ sb,
                                                   const int* __restrict__ rank,
                                                   const int* __restrict__ offs,
                                                   unsigned* __restrict__ meta,
                                                   const unsigned short* __restrict__ xb,
                                                   const unsigned short* __restrict__ Bp,
                                                   const float* __restrict__ bfv,
                                                   const float* __restrict__ bsv,
                                                   unsigned* __restrict__ Pd,
                                                   unsigned short* __restrict__ Ps8) {
    __shared__ __align__(16) short xl[32 * 64];
    const int r7 = blockIdx.x % 7;
    const int q7 = blockIdx.x / 7;
    if (r7 < 2) {
        __shared__ float swl[25], sbl[5];
        if (threadIdx.x < 25) swl[threadIdx.x] = sw[threadIdx.x];
        if (threadIdx.x >= 32 && threadIdx.x < 37) sbl[threadIdx.x - 32] = sb[threadIdx.x - 32];
        __syncthreads();
        const int base = (q7 * 2 + r7) * 1280 + threadIdx.x;
        int s[5], d[5], r[5];
        float ea[5][5];
#pragma unroll
        for (int j = 0; j < 5; j++) {
            const int e = base + j * 256;
            s[j] = ei[e];
            d[j] = ei[NE + e];
            r[j] = rank[e];
#pragma unroll
            for (int k = 0; k < 5; k++) ea[j][k] = eattr[(size_t)e * 5 + k];
        }
        int pos[5];
#pragma unroll
        for (int j = 0; j < 5; j++) pos[j] = offs[d[j]] + r[j];  // random load, no RMW
#pragma unroll
        for (int j = 0; j < 5; j++) {
            unsigned u5[5];
#pragma unroll
            for (int k = 0; k < 5; k++) {
                float a = sbl[k];
#pragma unroll
                for (int q = 0; q < 5; q++) a += ea[j][q] * swl[q * 5 + k];
                u5[k] = f2bf(fmaxf(a, 0.f));
            }
            u32x4 m;
            m[0] = (unsigned)s[j];
            m[1] = u5[0] | (u5[1] << 16);
            m[2] = u5[2] | (u5[3] << 16);
            m[3] = u5[4];
            __builtin_nontemporal_store(m, (u32x4*)&meta[(size_t)pos[j] * 4]);
        }
        return;
    }
    // ---- projm path (layer 0) ----
    const int rowbase = (q7 * 5 + (r7 - 2)) * 32;
    {
        const u32x4* xsrc = (const u32x4*)(xb + (size_t)rowbase * 64);
        const int i = threadIdx.x;
        const u32x4 v = __builtin_nontemporal_load(&xsrc[i]);
        *(u32x4*)&xl[swz(i >> 3, i & 7)] = v;
    }
    __syncthreads();
    const int ct = threadIdx.x >> 6;
    const int l = threadIdx.x & 63;
    const int lm = l & 15;
    const int g = l >> 4;
    short8v A[2][2];
#pragma unroll
    for (int rt = 0; rt < 2; rt++) frag_reads(xl, rt * 16 + lm, g, A[rt][0], A[rt][1]);
    const short* bp = (const short*)Bp;
    f32x4 acc[4][2];
#pragma unroll
    for (int m = 0; m < 4; m++) {
        const short8v B0 = *(const short8v*)&bp[(((m * 4 + ct) * 2 + 0) * 64 + l) * 8];
        const short8v B1 = *(const short8v*)&bp[(((m * 4 + ct) * 2 + 1) * 64 + l) * 8];
#pragma unroll
        for (int rt = 0; rt < 2; rt++) {
            f32x4 a = {0.f, 0.f, 0.f, 0.f};
            a = __builtin_amdgcn_mfma_f32_16x16x32_bf16(A[rt][0], B0, a, 0, 0, 0);
            a = __builtin_amdgcn_mfma_f32_16x16x32_bf16(A[rt][1], B1, a, 0, 0, 0);
            acc[m][rt] = a;
        }
    }
    const int col = ct * 16 + lm;
    const float bfb = -LOG2E * bfv[col];
    const float bsb = LOG2E * bsv[col];
#pragma unroll
    for (int rt = 0; rt < 2; rt++) {
#pragma unroll
        for (int reg = 0; reg < 4; reg++) {
            const int rowg = rowbase + rt * 16 + g * 4 + reg;
            Pd[(size_t)rowg * 64 + col] =
                f2bf(acc[0][rt][reg] + bfb) | (f2bf(acc[1][rt][reg] + bsb) << 16);
            Ps8[(size_t)rowg * 64 + col] = (unsigned short)__builtin_amdgcn_cvt_pk_fp8_f32(
                acc[2][rt][reg], acc[3][rt][reg], 0, false);
        }
    }
}

// ---------------------------------------------------------------------------
// MFMA projections (standalone, layer 1), 32 rows per block, swizzled LDS.
__global__ __launch_bounds__(256) void k_projm(const unsigned short* __restrict__ xb,
                                               const unsigned short* __restrict__ Bp,
                                               const float* __restrict__ bfv,
                                               const float* __restrict__ bsv,
                                               unsigned* __restrict__ Pd,
                                               unsigned short* __restrict__ Ps8) {
    __shared__ __align__(16) short xl[32 * 64];
    const int rowbase = blockIdx.x * 32;
    {
        const u32x4* xsrc = (const u32x4*)(xb + (size_t)rowbase * 64);
        const int i = threadIdx.x;
        const u32x4 v = __builtin_nontemporal_load(&xsrc[i]);
        *(u32x4*)&xl[swz(i >> 3, i & 7)] = v;
    }
    __syncthreads();
    const int ct = threadIdx.x >> 6;
    const int l = threadIdx.x & 63;
    const int lm = l & 15;
    const int g = l >> 4;
    short8v A[2][2];
#pragma unroll
    for (int rt = 0; rt < 2; rt++) frag_reads(xl, rt * 16 + lm, g, A[rt][0], A[rt][1]);
    const short* bp = (const short*)Bp;
    f32x4 acc[4][2];
#pragma unroll
    for (int m = 0; m < 4; m++) {
        const short8v B0 = *(const short8v*)&bp[(((m * 4 + ct) * 2 + 0) * 64 + l) * 8];
        const short8v B1 = *(const short8v*)&bp[(((m * 4 + ct) * 2 + 1) * 64 + l) * 8];
#pragma unroll
        for (int rt = 0; rt < 2; rt++) {
            f32x4 a = {0.f, 0.f, 0.f, 0.f};
            a = __builtin_amdgcn_mfma_f32_16x16x32_bf16(A[rt][0], B0, a, 0, 0, 0);
            a = __builtin_amdgcn_mfma_f32_16x16x32_bf16(A[rt][1], B1, a, 0, 0, 0);
            acc[m][rt] = a;
        }
    }
    const int col = ct * 16 + lm;
    const float bfb = -LOG2E * bfv[col];
    const float bsb = LOG2E * bsv[col];
#pragma unroll
    for (int rt = 0; rt < 2; rt++) {
#pragma unroll
        for (int reg = 0; reg < 4; reg++) {
            const int rowg = rowbase + rt * 16 + g * 4 + reg;
            Pd[(size_t)rowg * 64 + col] =
                f2bf(acc[0][rt][reg] + bfb) | (f2bf(acc[1][rt][reg] + bsb) << 16);
            Ps8[(size_t)rowg * 64 + col] = (unsigned short)__builtin_amdgcn_cvt_pk_fp8_f32(
                acc[2][rt][reg], acc[3][rt][reg], 0, false);
        }
    }
}

// ---------------------------------------------------------------------------
// Segment aggregation: ONE WAVE = ONE BLOCK = ONE NODE (64-thread blocks;
// 1-wave WGs retire independently -> best wave-slot refill, round-12 result).
// Width-4 batch, meta 2 batches ahead (scalar), fp8 Ps gathers 1 ahead.
// Dual accumulator breaks the serial fmaf chain within each batch.
__global__ __launch_bounds__(64) void k_seg(const int* __restrict__ offs,
                                            const uint4* __restrict__ meta,
                                            const unsigned* __restrict__ Pd,
                                            const unsigned short* __restrict__ Ps8,
                                            const float* __restrict__ wfE,
                                            const float* __restrict__ wsE,
                                            const unsigned short* __restrict__ xbin,
                                            float* __restrict__ outf,
                                            unsigned short* __restrict__ xbout) {
    const int n = blockIdx.x;
    const int lane = threadIdx.x;
    const int start = __builtin_amdgcn_readfirstlane(offs[n]);
    const int end = __builtin_amdgcn_readfirstlane(offs[n + 1]);
    const unsigned pd = __builtin_nontemporal_load(&Pd[(size_t)n * 64 + lane]);
    f32x2 pd2;
    pd2.x = bflo(pd);
    pd2.y = bfhi(pd);
    f32x2 w2[5];
#pragma unroll
    for (int k = 0; k < 5; k++) {
        f32x2 p;
        p.x = -LOG2E * wfE[k * 64 + lane];
        p.y = LOG2E * wsE[k * 64 + lane];
        w2[k] = p;
    }
    const float xv = bflo((unsigned)xbin[(size_t)n * 64 + lane]);
    float acc0 = 0.f, acc1 = 0.f;
    const int cnt = end - start;
    if (cnt > 0) {
        const int last = end - 1;
        const int nbF = (cnt + 3) >> 2;
        uint4 M0[4], M1[4];
        unsigned PS0[4];
#pragma unroll
        for (int j = 0; j < 4; j++) M0[j] = meta[imin(start + j, last)];
#pragma unroll
        for (int j = 0; j < 4; j++) M1[j] = meta[imin(start + 4 + j, last)];
#pragma unroll
        for (int j = 0; j < 4; j++) PS0[j] = Ps8[(size_t)M0[j].x * 64 + lane];
        for (int b = 0; b < nbF - 1; b++) {
            const int base2 = __builtin_amdgcn_readfirstlane(start + (b + 2) * 4);
            uint4 M2[4];
            unsigned PS1[4];
#pragma unroll
            for (int j = 0; j < 4; j++) M2[j] = meta[imin(base2 + j, last)];
#pragma unroll
            for (int j = 0; j < 4; j++) PS1[j] = Ps8[(size_t)M1[j].x * 64 + lane];
            acc0 = edge_acc(M0[0], PS0[0], pd2, w2, acc0);
            acc1 = edge_acc(M0[1], PS0[1], pd2, w2, acc1);
            acc0 = edge_acc(M0[2], PS0[2], pd2, w2, acc0);
            acc1 = edge_acc(M0[3], PS0[3], pd2, w2, acc1);
#pragma unroll
            for (int j = 0; j < 4; j++) {
                M0[j] = M1[j];
                M1[j] = M2[j];
                PS0[j] = PS1[j];
            }
        }
        const int lb = start + (nbF - 1) * 4;
        if (lb + 0 < end) acc0 = edge_acc(M0[0], PS0[0], pd2, w2, acc0);
        if (lb + 1 < end) acc1 = edge_acc(M0[1], PS0[1], pd2, w2, acc1);
        if (lb + 2 < end) acc0 = edge_acc(M0[2], PS0[2], pd2, w2, acc0);
        if (lb + 3 < end) acc1 = edge_acc(M0[3], PS0[3], pd2, w2, acc1);
    }
    const float res = fmaxf(fmaf(acc0 + acc1, LN2, xv), 0.f);
    if (outf) {
        __builtin_nontemporal_store(res, &outf[(size_t)n * 64 + lane]);  // final f32
    } else {
        xbout[(size_t)n * 64 + lane] = (unsigned short)f2bf(res);  // XB in-place
    }
}

// ---------------------------------------------------------------------------
extern "C" void kernel_launch(void* const* d_in, const int* in_sizes, int n_in,
                              void* d_out, int out_size, void* d_ws, size_t ws_size,
                              hipStream_t stream) {
    const float* h = (const float*)d_in[0];
    const int* ei = (const int*)d_in[1];
    const float* eattr = (const float*)d_in[3];
    const float* lin0_w = (const float*)d_in[5];
    const float* lin0_b = (const float*)d_in[6];
    const float* short_w = (const float*)d_in[7];
    const float* short_b = (const float*)d_in[8];
    const float* conv_f_w = (const float*)d_in[9];
    const float* conv_f_b = (const float*)d_in[10];
    const float* conv_s_w = (const float*)d_in[11];
    const float* conv_s_b = (const float*)d_in[12];

    char* ws = (char*)d_ws;
    uint4* meta = (uint4*)ws;                             // [NE] 16B, 25.6 MB
    unsigned* Pd = (unsigned*)(ws + (size_t)NE * 16);     // [NN*64] u32 (bf16 pair)
    unsigned short* Ps8 = (unsigned short*)(Pd + (size_t)NN * 64);  // [NN*64] u16 (fp8 pair)
    unsigned short* XB = Ps8 + (size_t)NN * 64;           // [NN*64] bf16 node features
    unsigned short* Bp = XB + (size_t)NN * 64;            // [2][16384]+[4096] packed weights
    int* cnt = (int*)(Bp + 36864);                        // [NN]
    int* offs = cnt + NN;                                 // [NN+1]
    int* bsum = offs + NN + 1;                            // [NSB]
    int* rank = bsum + NSB;                               // [NE]

    hipMemsetAsync(cnt, 0, (size_t)NN * 4, stream);
    k_wpack<<<18, 256, 0, stream>>>(conv_f_w, conv_s_w, lin0_w, Bp);
    k_lin0m_hist<<<4375, 256, 0, stream>>>(h, Bp + 32768, lin0_b, XB, ei, cnt, rank);
    k_scan1<<<NSB, 256, 0, stream>>>(cnt, offs, bsum);
    k_scan2<<<1, 512, 0, stream>>>(bsum);
    k_scan3<<<NSB, 256, 0, stream>>>(offs, bsum);
    // layer 0: scatter fused with projm (mod-7 interleaved, overlapped)
    k_scat_proj<<<4375, 256, 0, stream>>>(ei, eattr, short_w, short_b, rank, offs,
                                          (unsigned*)meta, XB, Bp, conv_f_b, conv_s_b,
                                          Pd, Ps8);
    k_seg<<<NN, 64, 0, stream>>>(offs, meta, Pd, Ps8,
                                 conv_f_w + 128 * 64, conv_s_w + 128 * 64,
                                 XB, nullptr, XB);
    // layer 1
    k_projm<<<NN / 32, 256, 0, stream>>>(XB, Bp + 16384, conv_f_b + 64, conv_s_b + 64, Pd, Ps8);
    k_seg<<<NN, 64, 0, stream>>>(offs, meta, Pd, Ps8,
                                 conv_f_w + 133 * 64 + 128 * 64,
                                 conv_s_w + 133 * 64 + 128 * 64,
                                 XB, (float*)d_out, nullptr);
}

// Round 17
// 298.749 us; speedup vs baseline: 1.0507x; 1.0348x over previous
//
#include <hip/hip_runtime.h>

#define NN 100000
#define NE 1600000
#define NSB 391  // ceil(NN/256) scan blocks

#define LOG2E 1.4426950408889634f
#define LN2 0.6931471805599453f

typedef short short4v __attribute__((ext_vector_type(4)));
typedef short short8v __attribute__((ext_vector_type(8)));
typedef float f32x2 __attribute__((ext_vector_type(2)));
typedef float f32x4 __attribute__((ext_vector_type(4)));
typedef unsigned u32x2 __attribute__((ext_vector_type(2)));
typedef unsigned u32x4 __attribute__((ext_vector_type(4)));

static __device__ __forceinline__ unsigned f2bf(float x) {
    unsigned b = __float_as_uint(x);
    return (b + 0x7FFFu + ((b >> 16) & 1u)) >> 16;  // RNE bf16 bits
}
static __device__ __forceinline__ float bflo(unsigned u) { return __uint_as_float(u << 16); }
static __device__ __forceinline__ int imin(int a, int b) { return a < b ? a : b; }
static __device__ __forceinline__ short8v mk8(short4v a, short4v b) {
    short8v r;
    r[0] = a[0]; r[1] = a[1]; r[2] = a[2]; r[3] = a[3];
    r[4] = b[0]; r[5] = b[1]; r[6] = b[2]; r[7] = b[3];
    return r;
}

// Swizzled LDS tile address (shorts): [32][64] tile, 16B blocks XOR'd by row&7.
static __device__ __forceinline__ int swz(int row, int colblk) {
    return row * 64 + ((colblk ^ (row & 7)) << 3);
}

// Build one A fragment (16 shorts logical cols of a row).
static __device__ __forceinline__ void frag_reads(const short* xl, int row, int g,
                                                  short8v& a0, short8v& a1) {
    const int sub = (g & 1) * 4;
    const int cb = g >> 1;
    const short4v p0 = *(const short4v*)&xl[swz(row, cb + 0) + sub];
    const short4v p1 = *(const short4v*)&xl[swz(row, cb + 2) + sub];
    const short4v p2 = *(const short4v*)&xl[swz(row, cb + 4) + sub];
    const short4v p3 = *(const short4v*)&xl[swz(row, cb + 6) + sub];
    a0 = mk8(p0, p1);
    a1 = mk8(p2, p3);
}

// One edge's gated-message contribution. m = {src|fp8(e54)<<24, fp8x4(e50..e53)},
// ps = fp8-e4m3 pair (f,s). All unpacks via v_cvt_pk_f32_fp8.
static __device__ __forceinline__ float edge_acc(u32x2 m, unsigned ps, f32x2 pd2,
                                                 const f32x2* __restrict__ w2, float acc) {
    f32x2 z = __builtin_amdgcn_cvt_pk_f32_fp8((int)ps, false);
    z += pd2;
    const f32x2 e01 = __builtin_amdgcn_cvt_pk_f32_fp8((int)m.y, false);
    const f32x2 e23 = __builtin_amdgcn_cvt_pk_f32_fp8((int)m.y, true);
    const f32x2 e4x = __builtin_amdgcn_cvt_pk_f32_fp8((int)(m.x >> 24), false);
    z += e01.x * w2[0];
    z += e01.y * w2[1];
    z += e23.x * w2[2];
    z += e23.y * w2[3];
    z += e4x.x * w2[4];
    const float sig = __builtin_amdgcn_rcpf(1.f + __builtin_amdgcn_exp2f(z.x));
    const float gg = __builtin_amdgcn_logf(1.f + __builtin_amdgcn_exp2f(z.y));
    return fmaf(sig, gg, acc);
}

// ---------------------------------------------------------------------------
// Pack into MFMA B-fragment layout (2 conv layers x 4 mats + lin0).
__global__ __launch_bounds__(256) void k_wpack(const float* __restrict__ cfw,
                                               const float* __restrict__ csw,
                                               const float* __restrict__ l0w,
                                               unsigned short* __restrict__ Bp) {
    const int qq = blockIdx.x * 256 + threadIdx.x;  // 4608 total
    const float* src;
    float scale;
    int roff, ct, kh, l;
    if (qq < 4096) {
        const int layer = qq >> 11;
        const int q = qq & 2047;
        const int m = q >> 9;
        const int rem = q & 511;
        ct = rem >> 7;
        kh = (rem >> 6) & 1;
        l = rem & 63;
        scale = (m & 1) ? LOG2E : -LOG2E;
        src = ((m & 1) ? csw : cfw) + (size_t)layer * 133 * 64;
        roff = (m >> 1) ? 64 : 0;
    } else {
        const int p = qq - 4096;
        ct = p >> 7;
        kh = (p >> 6) & 1;
        l = p & 63;
        scale = 1.f;
        src = l0w;
        roff = 0;
    }
    const int n = ct * 16 + (l & 15);
#pragma unroll
    for (int j = 0; j < 8; j++) {
        const int k = kh * 32 + ((j < 4) ? (4 * (l >> 4) + j) : (16 + 4 * (l >> 4) + j - 4));
        Bp[(size_t)qq * 8 + j] = (unsigned short)f2bf(scale * src[(size_t)(roff + k) * 64 + n]);
    }
}

// ---------------------------------------------------------------------------
// Fused, mod-7 interleaved (4375 = 625*7):
//   blockIdx%7 < 2 : dst histogram + per-edge rank (latency role)
//   else           : XB = bf16(relu(h @ lin0_w + b)) via MFMA (compute role)
__global__ __launch_bounds__(256) void k_lin0m_hist(const float* __restrict__ h,
                                                    const unsigned short* __restrict__ Bp0,
                                                    const float* __restrict__ b,
                                                    unsigned short* __restrict__ xb,
                                                    const int* __restrict__ ei,
                                                    int* __restrict__ cnt,
                                                    int* __restrict__ rank) {
    __shared__ __align__(16) short xl[32 * 64];
    const int r7 = blockIdx.x % 7;
    const int q7 = blockIdx.x / 7;
    if (r7 < 2) {
        const int base = (q7 * 2 + r7) * 1280 + threadIdx.x;
        int r[5];
#pragma unroll
        for (int j = 0; j < 5; j++) r[j] = atomicAdd(&cnt[ei[NE + base + j * 256]], 1);
#pragma unroll
        for (int j = 0; j < 5; j++) rank[base + j * 256] = r[j];
        return;
    }
    const int rowbase = (q7 * 5 + (r7 - 2)) * 32;
    {
        const float4* hs = (const float4*)(h + (size_t)rowbase * 64);
#pragma unroll
        for (int it = 0; it < 2; it++) {
            const int i = threadIdx.x + it * 256;
            const float4 v = hs[i];
            short4v sv;
            sv[0] = (short)f2bf(v.x);
            sv[1] = (short)f2bf(v.y);
            sv[2] = (short)f2bf(v.z);
            sv[3] = (short)f2bf(v.w);
            const int row = i >> 4;
            *(short4v*)&xl[swz(row, (i >> 1) & 7) + (i & 1) * 4] = sv;
        }
    }
    __syncthreads();
    const int ct = threadIdx.x >> 6;
    const int l = threadIdx.x & 63;
    const int lm = l & 15;
    const int g = l >> 4;
    short8v A[2][2];
#pragma unroll
    for (int rt = 0; rt < 2; rt++) frag_reads(xl, rt * 16 + lm, g, A[rt][0], A[rt][1]);
    const short* bp = (const short*)Bp0;
    const short8v B0 = *(const short8v*)&bp[((ct * 2 + 0) * 64 + l) * 8];
    const short8v B1 = *(const short8v*)&bp[((ct * 2 + 1) * 64 + l) * 8];
    const int col = ct * 16 + lm;
    const float bc = b[col];
#pragma unroll
    for (int rt = 0; rt < 2; rt++) {
        f32x4 a = {0.f, 0.f, 0.f, 0.f};
        a = __builtin_amdgcn_mfma_f32_16x16x32_bf16(A[rt][0], B0, a, 0, 0, 0);
        a = __builtin_amdgcn_mfma_f32_16x16x32_bf16(A[rt][1], B1, a, 0, 0, 0);
#pragma unroll
        for (int reg = 0; reg < 4; reg++) {
            const int rowg = rowbase + rt * 16 + g * 4 + reg;
            xb[(size_t)rowg * 64 + col] = (unsigned short)f2bf(fmaxf(a[reg] + bc, 0.f));
        }
    }
}

// ---------------------------------------------------------------------------
__global__ __launch_bounds__(256) void k_scan1(const int* __restrict__ cnt,
                                               int* __restrict__ offs, int* __restrict__ bsum) {
    __shared__ int sm[256];
    const int t = threadIdx.x;
    const int i = blockIdx.x * 256 + t;
    const int v = (i < NN) ? cnt[i] : 0;
    sm[t] = v;
    __syncthreads();
    for (int off = 1; off < 256; off <<= 1) {
        const int x = (t >= off) ? sm[t - off] : 0;
        __syncthreads();
        sm[t] += x;
        __syncthreads();
    }
    if (i < NN) offs[i] = sm[t] - v;
    if (t == 255) bsum[blockIdx.x] = sm[255];
}

__global__ __launch_bounds__(512) void k_scan2(int* __restrict__ bsum) {
    __shared__ int sm[512];
    const int t = threadIdx.x;
    const int v = (t < NSB) ? bsum[t] : 0;
    sm[t] = v;
    __syncthreads();
    for (int off = 1; off < 512; off <<= 1) {
        const int x = (t >= off) ? sm[t - off] : 0;
        __syncthreads();
        sm[t] += x;
        __syncthreads();
    }
    if (t < NSB) bsum[t] = sm[t] - v;
}

__global__ __launch_bounds__(256) void k_scan3(int* __restrict__ offs,
                                               const int* __restrict__ bsum) {
    const int i = blockIdx.x * 256 + threadIdx.x;
    if (i < NN) offs[i] += bsum[blockIdx.x];
    if (i == 0) offs[NN] = NE;
}

// ---------------------------------------------------------------------------
// Fused, mod-7 interleaved: scatter (latency role) / MFMA proj layer 0.
// meta record = 8B: {src | fp8(e54)<<24, fp8x4(e50..e53)}; plain stores so L2
// absorbs partial-line writes (8 records per 64B line).
__global__ __launch_bounds__(256) void k_scat_proj(const int* __restrict__ ei,
                                                   const float* __restrict__ eattr,
                                                   const float* __restrict__ sw,
                                                   const float* __restrict__ sb,
                                                   const int* __restrict__ rank,
                                                   const int* __restrict__ offs,
                                                   u32x2* __restrict__ meta,
                                                   const unsigned short* __restrict__ xb,
                                                   const unsigned short* __restrict__ Bp,
                                                   const float* __restrict__ bfv,
                                                   const float* __restrict__ bsv,
                                                   unsigned* __restrict__ Pd,
                                                   unsigned short* __restrict__ Ps8) {
    __shared__ __align__(16) short xl[32 * 64];
    const int r7 = blockIdx.x % 7;
    const int q7 = blockIdx.x / 7;
    if (r7 < 2) {
        __shared__ float swl[25], sbl[5];
        if (threadIdx.x < 25) swl[threadIdx.x] = sw[threadIdx.x];
        if (threadIdx.x >= 32 && threadIdx.x < 37) sbl[threadIdx.x - 32] = sb[threadIdx.x - 32];
        __syncthreads();
        const int base = (q7 * 2 + r7) * 1280 + threadIdx.x;
        int s[5], d[5], r[5];
        float ea[5][5];
#pragma unroll
        for (int j = 0; j < 5; j++) {
            const int e = base + j * 256;
            s[j] = ei[e];
            d[j] = ei[NE + e];
            r[j] = rank[e];
#pragma unroll
            for (int k = 0; k < 5; k++) ea[j][k] = eattr[(size_t)e * 5 + k];
        }
        int pos[5];
#pragma unroll
        for (int j = 0; j < 5; j++) pos[j] = offs[d[j]] + r[j];  // random load, no RMW
#pragma unroll
        for (int j = 0; j < 5; j++) {
            float e5[5];
#pragma unroll
            for (int k = 0; k < 5; k++) {
                float a = sbl[k];
#pragma unroll
                for (int q = 0; q < 5; q++) a += ea[j][q] * swl[q * 5 + k];
                e5[k] = fmaxf(a, 0.f);
            }
            unsigned hi = (unsigned)__builtin_amdgcn_cvt_pk_fp8_f32(e5[0], e5[1], 0, false);
            hi = (unsigned)__builtin_amdgcn_cvt_pk_fp8_f32(e5[2], e5[3], (int)hi, true);
            const unsigned b4 =
                (unsigned)__builtin_amdgcn_cvt_pk_fp8_f32(e5[4], 0.f, 0, false) & 0xFFu;
            u32x2 m;
            m.x = (unsigned)s[j] | (b4 << 24);
            m.y = hi;
            meta[pos[j]] = m;  // plain store: L2 write-combines within lines
        }
        return;
    }
    // ---- projm path (layer 0) ----
    const int rowbase = (q7 * 5 + (r7 - 2)) * 32;
    {
        const u32x4* xsrc = (const u32x4*)(xb + (size_t)rowbase * 64);
        const int i = threadIdx.x;
        const u32x4 v = __builtin_nontemporal_load(&xsrc[i]);
        *(u32x4*)&xl[swz(i >> 3, i & 7)] = v;
    }
    __syncthreads();
    const int ct = threadIdx.x >> 6;
    const int l = threadIdx.x & 63;
    const int lm = l & 15;
    const int g = l >> 4;
    short8v A[2][2];
#pragma unroll
    for (int rt = 0; rt < 2; rt++) frag_reads(xl, rt * 16 + lm, g, A[rt][0], A[rt][1]);
    const short* bp = (const short*)Bp;
    f32x4 acc[4][2];
#pragma unroll
    for (int m = 0; m < 4; m++) {
        const short8v B0 = *(const short8v*)&bp[(((m * 4 + ct) * 2 + 0) * 64 + l) * 8];
        const short8v B1 = *(const short8v*)&bp[(((m * 4 + ct) * 2 + 1) * 64 + l) * 8];
#pragma unroll
        for (int rt = 0; rt < 2; rt++) {
            f32x4 a = {0.f, 0.f, 0.f, 0.f};
            a = __builtin_amdgcn_mfma_f32_16x16x32_bf16(A[rt][0], B0, a, 0, 0, 0);
            a = __builtin_amdgcn_mfma_f32_16x16x32_bf16(A[rt][1], B1, a, 0, 0, 0);
            acc[m][rt] = a;
        }
    }
    const int col = ct * 16 + lm;
    const float bfb = -LOG2E * bfv[col];
    const float bsb = LOG2E * bsv[col];
#pragma unroll
    for (int rt = 0; rt < 2; rt++) {
#pragma unroll
        for (int reg = 0; reg < 4; reg++) {
            const int rowg = rowbase + rt * 16 + g * 4 + reg;
            Pd[(size_t)rowg * 64 + col] =
                f2bf(acc[0][rt][reg] + bfb) | (f2bf(acc[1][rt][reg] + bsb) << 16);
            Ps8[(size_t)rowg * 64 + col] = (unsigned short)__builtin_amdgcn_cvt_pk_fp8_f32(
                acc[2][rt][reg], acc[3][rt][reg], 0, false);
        }
    }
}

// ---------------------------------------------------------------------------
// MFMA projections (standalone, layer 1), 32 rows per block, swizzled LDS.
__global__ __launch_bounds__(256) void k_projm(const unsigned short* __restrict__ xb,
                                               const unsigned short* __restrict__ Bp,
                                               const float* __restrict__ bfv,
                                               const float* __restrict__ bsv,
                                               unsigned* __restrict__ Pd,
                                               unsigned short* __restrict__ Ps8) {
    __shared__ __align__(16) short xl[32 * 64];
    const int rowbase = blockIdx.x * 32;
    {
        const u32x4* xsrc = (const u32x4*)(xb + (size_t)rowbase * 64);
        const int i = threadIdx.x;
        const u32x4 v = __builtin_nontemporal_load(&xsrc[i]);
        *(u32x4*)&xl[swz(i >> 3, i & 7)] = v;
    }
    __syncthreads();
    const int ct = threadIdx.x >> 6;
    const int l = threadIdx.x & 63;
    const int lm = l & 15;
    const int g = l >> 4;
    short8v A[2][2];
#pragma unroll
    for (int rt = 0; rt < 2; rt++) frag_reads(xl, rt * 16 + lm, g, A[rt][0], A[rt][1]);
    const short* bp = (const short*)Bp;
    f32x4 acc[4][2];
#pragma unroll
    for (int m = 0; m < 4; m++) {
        const short8v B0 = *(const short8v*)&bp[(((m * 4 + ct) * 2 + 0) * 64 + l) * 8];
        const short8v B1 = *(const short8v*)&bp[(((m * 4 + ct) * 2 + 1) * 64 + l) * 8];
#pragma unroll
        for (int rt = 0; rt < 2; rt++) {
            f32x4 a = {0.f, 0.f, 0.f, 0.f};
            a = __builtin_amdgcn_mfma_f32_16x16x32_bf16(A[rt][0], B0, a, 0, 0, 0);
            a = __builtin_amdgcn_mfma_f32_16x16x32_bf16(A[rt][1], B1, a, 0, 0, 0);
            acc[m][rt] = a;
        }
    }
    const int col = ct * 16 + lm;
    const float bfb = -LOG2E * bfv[col];
    const float bsb = LOG2E * bsv[col];
#pragma unroll
    for (int rt = 0; rt < 2; rt++) {
#pragma unroll
        for (int reg = 0; reg < 4; reg++) {
            const int rowg = rowbase + rt * 16 + g * 4 + reg;
            Pd[(size_t)rowg * 64 + col] =
                f2bf(acc[0][rt][reg] + bfb) | (f2bf(acc[1][rt][reg] + bsb) << 16);
            Ps8[(size_t)rowg * 64 + col] = (unsigned short)__builtin_amdgcn_cvt_pk_fp8_f32(
                acc[2][rt][reg], acc[3][rt][reg], 0, false);
        }
    }
}

// ---------------------------------------------------------------------------
// Segment aggregation: ONE WAVE = ONE BLOCK = ONE NODE (64-thread blocks).
// Width-4 batch; meta (8B, scalar) 3 batches ahead; Ps gathers 2 batches ahead
// (PS0/PS1/PS2) -> ~2 batch-computes (~400+ cyc) of L2/L3 latency coverage.
__global__ __launch_bounds__(64) void k_seg(const int* __restrict__ offs,
                                            const u32x2* __restrict__ meta,
                                            const unsigned* __restrict__ Pd,
                                            const unsigned short* __restrict__ Ps8,
                                            const float* __restrict__ wfE,
                                            const float* __restrict__ wsE,
                                            const unsigned short* __restrict__ xbin,
                                            float* __restrict__ outf,
                                            unsigned short* __restrict__ xbout) {
    const int n = blockIdx.x;
    const int lane = threadIdx.x;
    const int start = __builtin_amdgcn_readfirstlane(offs[n]);
    const int end = __builtin_amdgcn_readfirstlane(offs[n + 1]);
    const unsigned pd = __builtin_nontemporal_load(&Pd[(size_t)n * 64 + lane]);
    f32x2 pd2;
    pd2.x = bflo(pd);
    pd2.y = __uint_as_float(pd & 0xFFFF0000u);
    f32x2 w2[5];
#pragma unroll
    for (int k = 0; k < 5; k++) {
        f32x2 p;
        p.x = -LOG2E * wfE[k * 64 + lane];
        p.y = LOG2E * wsE[k * 64 + lane];
        w2[k] = p;
    }
    const float xv = bflo((unsigned)xbin[(size_t)n * 64 + lane]);
    float acc0 = 0.f, acc1 = 0.f;
    const int cnt = end - start;
    if (cnt > 0) {
        const int last = end - 1;
        const int nbF = (cnt + 3) >> 2;
        u32x2 M0[4], M1[4], M2[4];
        unsigned PS0[4], PS1[4];
#pragma unroll
        for (int j = 0; j < 4; j++) M0[j] = meta[imin(start + j, last)];
#pragma unroll
        for (int j = 0; j < 4; j++) M1[j] = meta[imin(start + 4 + j, last)];
#pragma unroll
        for (int j = 0; j < 4; j++) M2[j] = meta[imin(start + 8 + j, last)];
#pragma unroll
        for (int j = 0; j < 4; j++) PS0[j] = Ps8[(size_t)(M0[j].x & 0xFFFFFFu) * 64 + lane];
#pragma unroll
        for (int j = 0; j < 4; j++) PS1[j] = Ps8[(size_t)(M1[j].x & 0xFFFFFFu) * 64 + lane];
        for (int b = 0; b < nbF - 1; b++) {
            const int base3 = __builtin_amdgcn_readfirstlane(start + (b + 3) * 4);
            u32x2 M3[4];
            unsigned PS2[4];
#pragma unroll
            for (int j = 0; j < 4; j++) M3[j] = meta[imin(base3 + j, last)];
#pragma unroll
            for (int j = 0; j < 4; j++) PS2[j] = Ps8[(size_t)(M2[j].x & 0xFFFFFFu) * 64 + lane];
            acc0 = edge_acc(M0[0], PS0[0], pd2, w2, acc0);
            acc1 = edge_acc(M0[1], PS0[1], pd2, w2, acc1);
            acc0 = edge_acc(M0[2], PS0[2], pd2, w2, acc0);
            acc1 = edge_acc(M0[3], PS0[3], pd2, w2, acc1);
#pragma unroll
            for (int j = 0; j < 4; j++) {
                M0[j] = M1[j];
                M1[j] = M2[j];
                M2[j] = M3[j];
                PS0[j] = PS1[j];
                PS1[j] = PS2[j];
            }
        }
        const int lb = start + (nbF - 1) * 4;
        if (lb + 0 < end) acc0 = edge_acc(M0[0], PS0[0], pd2, w2, acc0);
        if (lb + 1 < end) acc1 = edge_acc(M0[1], PS0[1], pd2, w2, acc1);
        if (lb + 2 < end) acc0 = edge_acc(M0[2], PS0[2], pd2, w2, acc0);
        if (lb + 3 < end) acc1 = edge_acc(M0[3], PS0[3], pd2, w2, acc1);
    }
    const float res = fmaxf(fmaf(acc0 + acc1, LN2, xv), 0.f);
    if (outf) {
        __builtin_nontemporal_store(res, &outf[(size_t)n * 64 + lane]);  // final f32
    } else {
        xbout[(size_t)n * 64 + lane] = (unsigned short)f2bf(res);  // XB in-place
    }
}

// ---------------------------------------------------------------------------
extern "C" void kernel_launch(void* const* d_in, const int* in_sizes, int n_in,
                              void* d_out, int out_size, void* d_ws, size_t ws_size,
                              hipStream_t stream) {
    const float* h = (const float*)d_in[0];
    const int* ei = (const int*)d_in[1];
    const float* eattr = (const float*)d_in[3];
    const float* lin0_w = (const float*)d_in[5];
    const float* lin0_b = (const float*)d_in[6];
    const float* short_w = (const float*)d_in[7];
    const float* short_b = (const float*)d_in[8];
    const float* conv_f_w = (const float*)d_in[9];
    const float* conv_f_b = (const float*)d_in[10];
    const float* conv_s_w = (const float*)d_in[11];
    const float* conv_s_b = (const float*)d_in[12];

    char* ws = (char*)d_ws;
    u32x2* meta = (u32x2*)ws;                             // [NE] 8B, 12.8 MB
    unsigned* Pd = (unsigned*)(ws + (size_t)NE * 8);      // [NN*64] u32 (bf16 pair)
    unsigned short* Ps8 = (unsigned short*)(Pd + (size_t)NN * 64);  // [NN*64] u16 (fp8 pair)
    unsigned short* XB = Ps8 + (size_t)NN * 64;           // [NN*64] bf16 node features
    unsigned short* Bp = XB + (size_t)NN * 64;            // [2][16384]+[4096] packed weights
    int* cnt = (int*)(Bp + 36864);                        // [NN]
    int* offs = cnt + NN;                                 // [NN+1]
    int* bsum = offs + NN + 1;                            // [NSB]
    int* rank = bsum + NSB;                               // [NE]

    hipMemsetAsync(cnt, 0, (size_t)NN * 4, stream);
    k_wpack<<<18, 256, 0, stream>>>(conv_f_w, conv_s_w, lin0_w, Bp);
    k_lin0m_hist<<<4375, 256, 0, stream>>>(h, Bp + 32768, lin0_b, XB, ei, cnt, rank);
    k_scan1<<<NSB, 256, 0, stream>>>(cnt, offs, bsum);
    k_scan2<<<1, 512, 0, stream>>>(bsum);
    k_scan3<<<NSB, 256, 0, stream>>>(offs, bsum);
    // layer 0: scatter fused with projm (mod-7 interleaved, overlapped)
    k_scat_proj<<<4375, 256, 0, stream>>>(ei, eattr, short_w, short_b, rank, offs,
                                          meta, XB, Bp, conv_f_b, conv_s_b, Pd, Ps8);
    k_seg<<<NN, 64, 0, stream>>>(offs, meta, Pd, Ps8,
                                 conv_f_w + 128 * 64, conv_s_w + 128 * 64,
                                 XB, nullptr, XB);
    // layer 1
    k_projm<<<NN / 32, 256, 0, stream>>>(XB, Bp + 16384, conv_f_b + 64, conv_s_b + 64, Pd, Ps8);
    k_seg<<<NN, 64, 0, stream>>>(offs, meta, Pd, Ps8,
                                 conv_f_w + 133 * 64 + 128 * 64,
                                 conv_s_w + 133 * 64 + 128 * 64,
                                 XB, (float*)d_out, nullptr);
}

// Round 18
// 286.296 us; speedup vs baseline: 1.0964x; 1.0435x over previous
//
#include <hip/hip_runtime.h>

#define NN 100000
#define NE 1600000
#define NSB 391  // ceil(NN/256) scan blocks

#define LOG2E 1.4426950408889634f
#define LN2 0.6931471805599453f

typedef short short4v __attribute__((ext_vector_type(4)));
typedef short short8v __attribute__((ext_vector_type(8)));
typedef float f32x2 __attribute__((ext_vector_type(2)));
typedef float f32x4 __attribute__((ext_vector_type(4)));
typedef unsigned u32x2 __attribute__((ext_vector_type(2)));
typedef unsigned u32x4 __attribute__((ext_vector_type(4)));

static __device__ __forceinline__ unsigned f2bf(float x) {
    unsigned b = __float_as_uint(x);
    return (b + 0x7FFFu + ((b >> 16) & 1u)) >> 16;  // RNE bf16 bits
}
static __device__ __forceinline__ float bflo(unsigned u) { return __uint_as_float(u << 16); }
static __device__ __forceinline__ int imin(int a, int b) { return a < b ? a : b; }
static __device__ __forceinline__ short8v mk8(short4v a, short4v b) {
    short8v r;
    r[0] = a[0]; r[1] = a[1]; r[2] = a[2]; r[3] = a[3];
    r[4] = b[0]; r[5] = b[1]; r[6] = b[2]; r[7] = b[3];
    return r;
}

// Swizzled LDS tile address (shorts): [32][64] tile, 16B blocks XOR'd by row&7.
static __device__ __forceinline__ int swz(int row, int colblk) {
    return row * 64 + ((colblk ^ (row & 7)) << 3);
}

// Build one A fragment (16 shorts logical cols of a row).
static __device__ __forceinline__ void frag_reads(const short* xl, int row, int g,
                                                  short8v& a0, short8v& a1) {
    const int sub = (g & 1) * 4;
    const int cb = g >> 1;
    const short4v p0 = *(const short4v*)&xl[swz(row, cb + 0) + sub];
    const short4v p1 = *(const short4v*)&xl[swz(row, cb + 2) + sub];
    const short4v p2 = *(const short4v*)&xl[swz(row, cb + 4) + sub];
    const short4v p3 = *(const short4v*)&xl[swz(row, cb + 6) + sub];
    a0 = mk8(p0, p1);
    a1 = mk8(p2, p3);
}

// One edge's gated-message contribution. m = {src|fp8(e54)<<24, fp8x4(e50..e53)},
// ps = fp8-e4m3 pair (f,s). All unpacks via v_cvt_pk_f32_fp8.
static __device__ __forceinline__ float edge_acc(u32x2 m, unsigned ps, f32x2 pd2,
                                                 const f32x2* __restrict__ w2, float acc) {
    f32x2 z = __builtin_amdgcn_cvt_pk_f32_fp8((int)ps, false);
    z += pd2;
    const f32x2 e01 = __builtin_amdgcn_cvt_pk_f32_fp8((int)m.y, false);
    const f32x2 e23 = __builtin_amdgcn_cvt_pk_f32_fp8((int)m.y, true);
    const f32x2 e4x = __builtin_amdgcn_cvt_pk_f32_fp8((int)(m.x >> 24), false);
    z += e01.x * w2[0];
    z += e01.y * w2[1];
    z += e23.x * w2[2];
    z += e23.y * w2[3];
    z += e4x.x * w2[4];
    const float sig = __builtin_amdgcn_rcpf(1.f + __builtin_amdgcn_exp2f(z.x));
    const float gg = __builtin_amdgcn_logf(1.f + __builtin_amdgcn_exp2f(z.y));
    return fmaf(sig, gg, acc);
}

// ---------------------------------------------------------------------------
// Pack into MFMA B-fragment layout (2 conv layers x 4 mats + lin0).
__global__ __launch_bounds__(256) void k_wpack(const float* __restrict__ cfw,
                                               const float* __restrict__ csw,
                                               const float* __restrict__ l0w,
                                               unsigned short* __restrict__ Bp) {
    const int qq = blockIdx.x * 256 + threadIdx.x;  // 4608 total
    const float* src;
    float scale;
    int roff, ct, kh, l;
    if (qq < 4096) {
        const int layer = qq >> 11;
        const int q = qq & 2047;
        const int m = q >> 9;
        const int rem = q & 511;
        ct = rem >> 7;
        kh = (rem >> 6) & 1;
        l = rem & 63;
        scale = (m & 1) ? LOG2E : -LOG2E;
        src = ((m & 1) ? csw : cfw) + (size_t)layer * 133 * 64;
        roff = (m >> 1) ? 64 : 0;
    } else {
        const int p = qq - 4096;
        ct = p >> 7;
        kh = (p >> 6) & 1;
        l = p & 63;
        scale = 1.f;
        src = l0w;
        roff = 0;
    }
    const int n = ct * 16 + (l & 15);
#pragma unroll
    for (int j = 0; j < 8; j++) {
        const int k = kh * 32 + ((j < 4) ? (4 * (l >> 4) + j) : (16 + 4 * (l >> 4) + j - 4));
        Bp[(size_t)qq * 8 + j] = (unsigned short)f2bf(scale * src[(size_t)(roff + k) * 64 + n]);
    }
}

// ---------------------------------------------------------------------------
// Fused, mod-7 interleaved (4375 = 625*7):
//   blockIdx%7 < 2 : dst histogram + per-edge rank (latency role)
//   else           : XB = bf16(relu(h @ lin0_w + b)) via MFMA (compute role)
__global__ __launch_bounds__(256) void k_lin0m_hist(const float* __restrict__ h,
                                                    const unsigned short* __restrict__ Bp0,
                                                    const float* __restrict__ b,
                                                    unsigned short* __restrict__ xb,
                                                    const int* __restrict__ ei,
                                                    int* __restrict__ cnt,
                                                    int* __restrict__ rank) {
    __shared__ __align__(16) short xl[32 * 64];
    const int r7 = blockIdx.x % 7;
    const int q7 = blockIdx.x / 7;
    if (r7 < 2) {
        const int base = (q7 * 2 + r7) * 1280 + threadIdx.x;
        int r[5];
#pragma unroll
        for (int j = 0; j < 5; j++) r[j] = atomicAdd(&cnt[ei[NE + base + j * 256]], 1);
#pragma unroll
        for (int j = 0; j < 5; j++) rank[base + j * 256] = r[j];
        return;
    }
    const int rowbase = (q7 * 5 + (r7 - 2)) * 32;
    {
        const float4* hs = (const float4*)(h + (size_t)rowbase * 64);
#pragma unroll
        for (int it = 0; it < 2; it++) {
            const int i = threadIdx.x + it * 256;
            const float4 v = hs[i];
            short4v sv;
            sv[0] = (short)f2bf(v.x);
            sv[1] = (short)f2bf(v.y);
            sv[2] = (short)f2bf(v.z);
            sv[3] = (short)f2bf(v.w);
            const int row = i >> 4;
            *(short4v*)&xl[swz(row, (i >> 1) & 7) + (i & 1) * 4] = sv;
        }
    }
    __syncthreads();
    const int ct = threadIdx.x >> 6;
    const int l = threadIdx.x & 63;
    const int lm = l & 15;
    const int g = l >> 4;
    short8v A[2][2];
#pragma unroll
    for (int rt = 0; rt < 2; rt++) frag_reads(xl, rt * 16 + lm, g, A[rt][0], A[rt][1]);
    const short* bp = (const short*)Bp0;
    const short8v B0 = *(const short8v*)&bp[((ct * 2 + 0) * 64 + l) * 8];
    const short8v B1 = *(const short8v*)&bp[((ct * 2 + 1) * 64 + l) * 8];
    const int col = ct * 16 + lm;
    const float bc = b[col];
#pragma unroll
    for (int rt = 0; rt < 2; rt++) {
        f32x4 a = {0.f, 0.f, 0.f, 0.f};
        a = __builtin_amdgcn_mfma_f32_16x16x32_bf16(A[rt][0], B0, a, 0, 0, 0);
        a = __builtin_amdgcn_mfma_f32_16x16x32_bf16(A[rt][1], B1, a, 0, 0, 0);
#pragma unroll
        for (int reg = 0; reg < 4; reg++) {
            const int rowg = rowbase + rt * 16 + g * 4 + reg;
            xb[(size_t)rowg * 64 + col] = (unsigned short)f2bf(fmaxf(a[reg] + bc, 0.f));
        }
    }
}

// ---------------------------------------------------------------------------
__global__ __launch_bounds__(256) void k_scan1(const int* __restrict__ cnt,
                                               int* __restrict__ offs, int* __restrict__ bsum) {
    __shared__ int sm[256];
    const int t = threadIdx.x;
    const int i = blockIdx.x * 256 + t;
    const int v = (i < NN) ? cnt[i] : 0;
    sm[t] = v;
    __syncthreads();
    for (int off = 1; off < 256; off <<= 1) {
        const int x = (t >= off) ? sm[t - off] : 0;
        __syncthreads();
        sm[t] += x;
        __syncthreads();
    }
    if (i < NN) offs[i] = sm[t] - v;
    if (t == 255) bsum[blockIdx.x] = sm[255];
}

__global__ __launch_bounds__(512) void k_scan2(int* __restrict__ bsum) {
    __shared__ int sm[512];
    const int t = threadIdx.x;
    const int v = (t < NSB) ? bsum[t] : 0;
    sm[t] = v;
    __syncthreads();
    for (int off = 1; off < 512; off <<= 1) {
        const int x = (t >= off) ? sm[t - off] : 0;
        __syncthreads();
        sm[t] += x;
        __syncthreads();
    }
    if (t < NSB) bsum[t] = sm[t] - v;
}

__global__ __launch_bounds__(256) void k_scan3(int* __restrict__ offs,
                                               const int* __restrict__ bsum) {
    const int i = blockIdx.x * 256 + threadIdx.x;
    if (i < NN) offs[i] += bsum[blockIdx.x];
    if (i == 0) offs[NN] = NE;
}

// ---------------------------------------------------------------------------
// Fused, mod-7 interleaved: scatter (latency role) / MFMA proj layer 0.
// meta record = 8B: {src | fp8(e54)<<24, fp8x4(e50..e53)}; plain stores so L2
// absorbs partial-line writes (8 records per 64B line).
__global__ __launch_bounds__(256) void k_scat_proj(const int* __restrict__ ei,
                                                   const float* __restrict__ eattr,
                                                   const float* __restrict__ sw,
                                                   const float* __restrict__ sb,
                                                   const int* __restrict__ rank,
                                                   const int* __restrict__ offs,
                                                   u32x2* __restrict__ meta,
                                                   const unsigned short* __restrict__ xb,
                                                   const unsigned short* __restrict__ Bp,
                                                   const float* __restrict__ bfv,
                                                   const float* __restrict__ bsv,
                                                   unsigned* __restrict__ Pd,
                                                   unsigned short* __restrict__ Ps8) {
    __shared__ __align__(16) short xl[32 * 64];
    const int r7 = blockIdx.x % 7;
    const int q7 = blockIdx.x / 7;
    if (r7 < 2) {
        __shared__ float swl[25], sbl[5];
        if (threadIdx.x < 25) swl[threadIdx.x] = sw[threadIdx.x];
        if (threadIdx.x >= 32 && threadIdx.x < 37) sbl[threadIdx.x - 32] = sb[threadIdx.x - 32];
        __syncthreads();
        const int base = (q7 * 2 + r7) * 1280 + threadIdx.x;
        int s[5], d[5], r[5];
        float ea[5][5];
#pragma unroll
        for (int j = 0; j < 5; j++) {
            const int e = base + j * 256;
            s[j] = ei[e];
            d[j] = ei[NE + e];
            r[j] = rank[e];
#pragma unroll
            for (int k = 0; k < 5; k++) ea[j][k] = eattr[(size_t)e * 5 + k];
        }
        int pos[5];
#pragma unroll
        for (int j = 0; j < 5; j++) pos[j] = offs[d[j]] + r[j];  // random load, no RMW
#pragma unroll
        for (int j = 0; j < 5; j++) {
            float e5[5];
#pragma unroll
            for (int k = 0; k < 5; k++) {
                float a = sbl[k];
#pragma unroll
                for (int q = 0; q < 5; q++) a += ea[j][q] * swl[q * 5 + k];
                e5[k] = fmaxf(a, 0.f);
            }
            unsigned hi = (unsigned)__builtin_amdgcn_cvt_pk_fp8_f32(e5[0], e5[1], 0, false);
            hi = (unsigned)__builtin_amdgcn_cvt_pk_fp8_f32(e5[2], e5[3], (int)hi, true);
            const unsigned b4 =
                (unsigned)__builtin_amdgcn_cvt_pk_fp8_f32(e5[4], 0.f, 0, false) & 0xFFu;
            u32x2 m;
            m.x = (unsigned)s[j] | (b4 << 24);
            m.y = hi;
            meta[pos[j]] = m;  // plain store: L2 write-combines within lines
        }
        return;
    }
    // ---- projm path (layer 0) ----
    const int rowbase = (q7 * 5 + (r7 - 2)) * 32;
    {
        const u32x4* xsrc = (const u32x4*)(xb + (size_t)rowbase * 64);
        const int i = threadIdx.x;
        const u32x4 v = __builtin_nontemporal_load(&xsrc[i]);
        *(u32x4*)&xl[swz(i >> 3, i & 7)] = v;
    }
    __syncthreads();
    const int ct = threadIdx.x >> 6;
    const int l = threadIdx.x & 63;
    const int lm = l & 15;
    const int g = l >> 4;
    short8v A[2][2];
#pragma unroll
    for (int rt = 0; rt < 2; rt++) frag_reads(xl, rt * 16 + lm, g, A[rt][0], A[rt][1]);
    const short* bp = (const short*)Bp;
    f32x4 acc[4][2];
#pragma unroll
    for (int m = 0; m < 4; m++) {
        const short8v B0 = *(const short8v*)&bp[(((m * 4 + ct) * 2 + 0) * 64 + l) * 8];
        const short8v B1 = *(const short8v*)&bp[(((m * 4 + ct) * 2 + 1) * 64 + l) * 8];
#pragma unroll
        for (int rt = 0; rt < 2; rt++) {
            f32x4 a = {0.f, 0.f, 0.f, 0.f};
            a = __builtin_amdgcn_mfma_f32_16x16x32_bf16(A[rt][0], B0, a, 0, 0, 0);
            a = __builtin_amdgcn_mfma_f32_16x16x32_bf16(A[rt][1], B1, a, 0, 0, 0);
            acc[m][rt] = a;
        }
    }
    const int col = ct * 16 + lm;
    const float bfb = -LOG2E * bfv[col];
    const float bsb = LOG2E * bsv[col];
#pragma unroll
    for (int rt = 0; rt < 2; rt++) {
#pragma unroll
        for (int reg = 0; reg < 4; reg++) {
            const int rowg = rowbase + rt * 16 + g * 4 + reg;
            Pd[(size_t)rowg * 64 + col] =
                f2bf(acc[0][rt][reg] + bfb) | (f2bf(acc[1][rt][reg] + bsb) << 16);
            Ps8[(size_t)rowg * 64 + col] = (unsigned short)__builtin_amdgcn_cvt_pk_fp8_f32(
                acc[2][rt][reg], acc[3][rt][reg], 0, false);
        }
    }
}

// ---------------------------------------------------------------------------
// MFMA projections (standalone, layer 1), 32 rows per block, swizzled LDS.
__global__ __launch_bounds__(256) void k_projm(const unsigned short* __restrict__ xb,
                                               const unsigned short* __restrict__ Bp,
                                               const float* __restrict__ bfv,
                                               const float* __restrict__ bsv,
                                               unsigned* __restrict__ Pd,
                                               unsigned short* __restrict__ Ps8) {
    __shared__ __align__(16) short xl[32 * 64];
    const int rowbase = blockIdx.x * 32;
    {
        const u32x4* xsrc = (const u32x4*)(xb + (size_t)rowbase * 64);
        const int i = threadIdx.x;
        const u32x4 v = __builtin_nontemporal_load(&xsrc[i]);
        *(u32x4*)&xl[swz(i >> 3, i & 7)] = v;
    }
    __syncthreads();
    const int ct = threadIdx.x >> 6;
    const int l = threadIdx.x & 63;
    const int lm = l & 15;
    const int g = l >> 4;
    short8v A[2][2];
#pragma unroll
    for (int rt = 0; rt < 2; rt++) frag_reads(xl, rt * 16 + lm, g, A[rt][0], A[rt][1]);
    const short* bp = (const short*)Bp;
    f32x4 acc[4][2];
#pragma unroll
    for (int m = 0; m < 4; m++) {
        const short8v B0 = *(const short8v*)&bp[(((m * 4 + ct) * 2 + 0) * 64 + l) * 8];
        const short8v B1 = *(const short8v*)&bp[(((m * 4 + ct) * 2 + 1) * 64 + l) * 8];
#pragma unroll
        for (int rt = 0; rt < 2; rt++) {
            f32x4 a = {0.f, 0.f, 0.f, 0.f};
            a = __builtin_amdgcn_mfma_f32_16x16x32_bf16(A[rt][0], B0, a, 0, 0, 0);
            a = __builtin_amdgcn_mfma_f32_16x16x32_bf16(A[rt][1], B1, a, 0, 0, 0);
            acc[m][rt] = a;
        }
    }
    const int col = ct * 16 + lm;
    const float bfb = -LOG2E * bfv[col];
    const float bsb = LOG2E * bsv[col];
#pragma unroll
    for (int rt = 0; rt < 2; rt++) {
#pragma unroll
        for (int reg = 0; reg < 4; reg++) {
            const int rowg = rowbase + rt * 16 + g * 4 + reg;
            Pd[(size_t)rowg * 64 + col] =
                f2bf(acc[0][rt][reg] + bfb) | (f2bf(acc[1][rt][reg] + bsb) << 16);
            Ps8[(size_t)rowg * 64 + col] = (unsigned short)__builtin_amdgcn_cvt_pk_fp8_f32(
                acc[2][rt][reg], acc[3][rt][reg], 0, false);
        }
    }
}

// ---------------------------------------------------------------------------
// Segment aggregation: ONE WAVE = ONE BLOCK = ONE NODE (64-thread blocks).
// Depth-2 pipeline (meta 2 batches ahead scalar, Ps 1 ahead): issues exactly
// one gather per edge (depth-3 wasted ~25% on prologue clamps). 8B fp8 meta.
__global__ __launch_bounds__(64) void k_seg(const int* __restrict__ offs,
                                            const u32x2* __restrict__ meta,
                                            const unsigned* __restrict__ Pd,
                                            const unsigned short* __restrict__ Ps8,
                                            const float* __restrict__ wfE,
                                            const float* __restrict__ wsE,
                                            const unsigned short* __restrict__ xbin,
                                            float* __restrict__ outf,
                                            unsigned short* __restrict__ xbout) {
    const int n = blockIdx.x;
    const int lane = threadIdx.x;
    const int start = __builtin_amdgcn_readfirstlane(offs[n]);
    const int end = __builtin_amdgcn_readfirstlane(offs[n + 1]);
    const unsigned pd = __builtin_nontemporal_load(&Pd[(size_t)n * 64 + lane]);
    f32x2 pd2;
    pd2.x = bflo(pd);
    pd2.y = __uint_as_float(pd & 0xFFFF0000u);
    f32x2 w2[5];
#pragma unroll
    for (int k = 0; k < 5; k++) {
        f32x2 p;
        p.x = -LOG2E * wfE[k * 64 + lane];
        p.y = LOG2E * wsE[k * 64 + lane];
        w2[k] = p;
    }
    const float xv = bflo((unsigned)xbin[(size_t)n * 64 + lane]);
    float acc0 = 0.f, acc1 = 0.f;
    const int cnt = end - start;
    if (cnt > 0) {
        const int last = end - 1;
        const int nbF = (cnt + 3) >> 2;
        u32x2 M0[4], M1[4];
        unsigned PS0[4];
#pragma unroll
        for (int j = 0; j < 4; j++) M0[j] = meta[imin(start + j, last)];
#pragma unroll
        for (int j = 0; j < 4; j++) M1[j] = meta[imin(start + 4 + j, last)];
#pragma unroll
        for (int j = 0; j < 4; j++) PS0[j] = Ps8[(size_t)(M0[j].x & 0xFFFFFFu) * 64 + lane];
        for (int b = 0; b < nbF - 1; b++) {
            const int base2 = __builtin_amdgcn_readfirstlane(start + (b + 2) * 4);
            u32x2 M2[4];
            unsigned PS1[4];
#pragma unroll
            for (int j = 0; j < 4; j++) M2[j] = meta[imin(base2 + j, last)];
#pragma unroll
            for (int j = 0; j < 4; j++) PS1[j] = Ps8[(size_t)(M1[j].x & 0xFFFFFFu) * 64 + lane];
            acc0 = edge_acc(M0[0], PS0[0], pd2, w2, acc0);
            acc1 = edge_acc(M0[1], PS0[1], pd2, w2, acc1);
            acc0 = edge_acc(M0[2], PS0[2], pd2, w2, acc0);
            acc1 = edge_acc(M0[3], PS0[3], pd2, w2, acc1);
#pragma unroll
            for (int j = 0; j < 4; j++) {
                M0[j] = M1[j];
                M1[j] = M2[j];
                PS0[j] = PS1[j];
            }
        }
        const int lb = start + (nbF - 1) * 4;
        if (lb + 0 < end) acc0 = edge_acc(M0[0], PS0[0], pd2, w2, acc0);
        if (lb + 1 < end) acc1 = edge_acc(M0[1], PS0[1], pd2, w2, acc1);
        if (lb + 2 < end) acc0 = edge_acc(M0[2], PS0[2], pd2, w2, acc0);
        if (lb + 3 < end) acc1 = edge_acc(M0[3], PS0[3], pd2, w2, acc1);
    }
    const float res = fmaxf(fmaf(acc0 + acc1, LN2, xv), 0.f);
    if (outf) {
        __builtin_nontemporal_store(res, &outf[(size_t)n * 64 + lane]);  // final f32
    } else {
        xbout[(size_t)n * 64 + lane] = (unsigned short)f2bf(res);  // XB in-place
    }
}

// ---------------------------------------------------------------------------
extern "C" void kernel_launch(void* const* d_in, const int* in_sizes, int n_in,
                              void* d_out, int out_size, void* d_ws, size_t ws_size,
                              hipStream_t stream) {
    const float* h = (const float*)d_in[0];
    const int* ei = (const int*)d_in[1];
    const float* eattr = (const float*)d_in[3];
    const float* lin0_w = (const float*)d_in[5];
    const float* lin0_b = (const float*)d_in[6];
    const float* short_w = (const float*)d_in[7];
    const float* short_b = (const float*)d_in[8];
    const float* conv_f_w = (const float*)d_in[9];
    const float* conv_f_b = (const float*)d_in[10];
    const float* conv_s_w = (const float*)d_in[11];
    const float* conv_s_b = (const float*)d_in[12];

    char* ws = (char*)d_ws;
    u32x2* meta = (u32x2*)ws;                             // [NE] 8B, 12.8 MB
    unsigned* Pd = (unsigned*)(ws + (size_t)NE * 8);      // [NN*64] u32 (bf16 pair)
    unsigned short* Ps8 = (unsigned short*)(Pd + (size_t)NN * 64);  // [NN*64] u16 (fp8 pair)
    unsigned short* XB = Ps8 + (size_t)NN * 64;           // [NN*64] bf16 node features
    unsigned short* Bp = XB + (size_t)NN * 64;            // [2][16384]+[4096] packed weights
    int* cnt = (int*)(Bp + 36864);                        // [NN]
    int* offs = cnt + NN;                                 // [NN+1]
    int* bsum = offs + NN + 1;                            // [NSB]
    int* rank = bsum + NSB;                               // [NE]

    hipMemsetAsync(cnt, 0, (size_t)NN * 4, stream);
    k_wpack<<<18, 256, 0, stream>>>(conv_f_w, conv_s_w, lin0_w, Bp);
    k_lin0m_hist<<<4375, 256, 0, stream>>>(h, Bp + 32768, lin0_b, XB, ei, cnt, rank);
    k_scan1<<<NSB, 256, 0, stream>>>(cnt, offs, bsum);
    k_scan2<<<1, 512, 0, stream>>>(bsum);
    k_scan3<<<NSB, 256, 0, stream>>>(offs, bsum);
    // layer 0: scatter fused with projm (mod-7 interleaved, overlapped)
    k_scat_proj<<<4375, 256, 0, stream>>>(ei, eattr, short_w, short_b, rank, offs,
                                          meta, XB, Bp, conv_f_b, conv_s_b, Pd, Ps8);
    k_seg<<<NN, 64, 0, stream>>>(offs, meta, Pd, Ps8,
                                 conv_f_w + 128 * 64, conv_s_w + 128 * 64,
                                 XB, nullptr, XB);
    // layer 1
    k_projm<<<NN / 32, 256, 0, stream>>>(XB, Bp + 16384, conv_f_b + 64, conv_s_b + 64, Pd, Ps8);
    k_seg<<<NN, 64, 0, stream>>>(offs, meta, Pd, Ps8,
                                 conv_f_w + 133 * 64 + 128 * 64,
                                 conv_s_w + 133 * 64 + 128 * 64,
                                 XB, (float*)d_out, nullptr);
}

// Round 19
// 283.372 us; speedup vs baseline: 1.1077x; 1.0103x over previous
//
#include <hip/hip_runtime.h>

#define NN 100000
#define NE 1600000
#define NSB 391  // ceil(NN/256) scan blocks

#define LOG2E 1.4426950408889634f
#define LN2 0.6931471805599453f

typedef short short4v __attribute__((ext_vector_type(4)));
typedef short short8v __attribute__((ext_vector_type(8)));
typedef float f32x2 __attribute__((ext_vector_type(2)));
typedef float f32x4 __attribute__((ext_vector_type(4)));
typedef unsigned u32x2 __attribute__((ext_vector_type(2)));
typedef unsigned u32x4 __attribute__((ext_vector_type(4)));

static __device__ __forceinline__ unsigned f2bf(float x) {
    unsigned b = __float_as_uint(x);
    return (b + 0x7FFFu + ((b >> 16) & 1u)) >> 16;  // RNE bf16 bits
}
static __device__ __forceinline__ float bflo(unsigned u) { return __uint_as_float(u << 16); }
static __device__ __forceinline__ int imin(int a, int b) { return a < b ? a : b; }
static __device__ __forceinline__ short8v mk8(short4v a, short4v b) {
    short8v r;
    r[0] = a[0]; r[1] = a[1]; r[2] = a[2]; r[3] = a[3];
    r[4] = b[0]; r[5] = b[1]; r[6] = b[2]; r[7] = b[3];
    return r;
}

// Swizzled LDS tile address (shorts): [32][64] tile, 16B blocks XOR'd by row&7.
static __device__ __forceinline__ int swz(int row, int colblk) {
    return row * 64 + ((colblk ^ (row & 7)) << 3);
}

// Build one A fragment (16 shorts logical cols of a row).
static __device__ __forceinline__ void frag_reads(const short* xl, int row, int g,
                                                  short8v& a0, short8v& a1) {
    const int sub = (g & 1) * 4;
    const int cb = g >> 1;
    const short4v p0 = *(const short4v*)&xl[swz(row, cb + 0) + sub];
    const short4v p1 = *(const short4v*)&xl[swz(row, cb + 2) + sub];
    const short4v p2 = *(const short4v*)&xl[swz(row, cb + 4) + sub];
    const short4v p3 = *(const short4v*)&xl[swz(row, cb + 6) + sub];
    a0 = mk8(p0, p1);
    a1 = mk8(p2, p3);
}

// One edge's gated-message contribution. m = {src|fp8(e54)<<24, fp8x4(e50..e53)},
// ps = fp8-e4m3 pair (f,s). All unpacks via v_cvt_pk_f32_fp8.
static __device__ __forceinline__ float edge_acc(u32x2 m, unsigned ps, f32x2 pd2,
                                                 const f32x2* __restrict__ w2, float acc) {
    f32x2 z = __builtin_amdgcn_cvt_pk_f32_fp8((int)ps, false);
    z += pd2;
    const f32x2 e01 = __builtin_amdgcn_cvt_pk_f32_fp8((int)m.y, false);
    const f32x2 e23 = __builtin_amdgcn_cvt_pk_f32_fp8((int)m.y, true);
    const f32x2 e4x = __builtin_amdgcn_cvt_pk_f32_fp8((int)(m.x >> 24), false);
    z += e01.x * w2[0];
    z += e01.y * w2[1];
    z += e23.x * w2[2];
    z += e23.y * w2[3];
    z += e4x.x * w2[4];
    const float sig = __builtin_amdgcn_rcpf(1.f + __builtin_amdgcn_exp2f(z.x));
    const float gg = __builtin_amdgcn_logf(1.f + __builtin_amdgcn_exp2f(z.y));
    return fmaf(sig, gg, acc);
}

// ---------------------------------------------------------------------------
// Pack weights:
//   qq in [0,4096):    conv-layer MFMA B fragments (LOG2E-scaled/sign-folded)
//   qq in [4096,4608): lin0 MFMA B fragments (unscaled)
//   qq in [4608,5248): W2 edge-weight table: f32x2 W2[2][5*64] =
//                      {-log2e*wfE[k*64+lane], log2e*wsE[k*64+lane]}
__global__ __launch_bounds__(256) void k_wpack(const float* __restrict__ cfw,
                                               const float* __restrict__ csw,
                                               const float* __restrict__ l0w,
                                               unsigned short* __restrict__ Bp,
                                               f32x2* __restrict__ W2) {
    const int qq = blockIdx.x * 256 + threadIdx.x;  // 5376 total (21 blocks)
    if (qq >= 5248) return;
    if (qq >= 4608) {
        const int q2 = qq - 4608;
        const int layer = q2 / 320;
        const int idx = q2 % 320;
        const float* wfL = cfw + (size_t)layer * 133 * 64 + 128 * 64;
        const float* wsL = csw + (size_t)layer * 133 * 64 + 128 * 64;
        f32x2 p;
        p.x = -LOG2E * wfL[idx];
        p.y = LOG2E * wsL[idx];
        W2[layer * 320 + idx] = p;
        return;
    }
    const float* src;
    float scale;
    int roff, ct, kh, l;
    if (qq < 4096) {
        const int layer = qq >> 11;
        const int q = qq & 2047;
        const int m = q >> 9;
        const int rem = q & 511;
        ct = rem >> 7;
        kh = (rem >> 6) & 1;
        l = rem & 63;
        scale = (m & 1) ? LOG2E : -LOG2E;
        src = ((m & 1) ? csw : cfw) + (size_t)layer * 133 * 64;
        roff = (m >> 1) ? 64 : 0;
    } else {
        const int p = qq - 4096;
        ct = p >> 7;
        kh = (p >> 6) & 1;
        l = p & 63;
        scale = 1.f;
        src = l0w;
        roff = 0;
    }
    const int n = ct * 16 + (l & 15);
#pragma unroll
    for (int j = 0; j < 8; j++) {
        const int k = kh * 32 + ((j < 4) ? (4 * (l >> 4) + j) : (16 + 4 * (l >> 4) + j - 4));
        Bp[(size_t)qq * 8 + j] = (unsigned short)f2bf(scale * src[(size_t)(roff + k) * 64 + n]);
    }
}

// ---------------------------------------------------------------------------
// Fused, mod-7 interleaved (4375 = 625*7):
//   blockIdx%7 < 2 : dst histogram + per-edge rank (latency role)
//   else           : XB = bf16(relu(h @ lin0_w + b)) via MFMA (compute role)
__global__ __launch_bounds__(256) void k_lin0m_hist(const float* __restrict__ h,
                                                    const unsigned short* __restrict__ Bp0,
                                                    const float* __restrict__ b,
                                                    unsigned short* __restrict__ xb,
                                                    const int* __restrict__ ei,
                                                    int* __restrict__ cnt,
                                                    int* __restrict__ rank) {
    __shared__ __align__(16) short xl[32 * 64];
    const int r7 = blockIdx.x % 7;
    const int q7 = blockIdx.x / 7;
    if (r7 < 2) {
        const int base = (q7 * 2 + r7) * 1280 + threadIdx.x;
        int r[5];
#pragma unroll
        for (int j = 0; j < 5; j++) r[j] = atomicAdd(&cnt[ei[NE + base + j * 256]], 1);
#pragma unroll
        for (int j = 0; j < 5; j++) rank[base + j * 256] = r[j];
        return;
    }
    const int rowbase = (q7 * 5 + (r7 - 2)) * 32;
    {
        const float4* hs = (const float4*)(h + (size_t)rowbase * 64);
#pragma unroll
        for (int it = 0; it < 2; it++) {
            const int i = threadIdx.x + it * 256;
            const float4 v = hs[i];
            short4v sv;
            sv[0] = (short)f2bf(v.x);
            sv[1] = (short)f2bf(v.y);
            sv[2] = (short)f2bf(v.z);
            sv[3] = (short)f2bf(v.w);
            const int row = i >> 4;
            *(short4v*)&xl[swz(row, (i >> 1) & 7) + (i & 1) * 4] = sv;
        }
    }
    __syncthreads();
    const int ct = threadIdx.x >> 6;
    const int l = threadIdx.x & 63;
    const int lm = l & 15;
    const int g = l >> 4;
    short8v A[2][2];
#pragma unroll
    for (int rt = 0; rt < 2; rt++) frag_reads(xl, rt * 16 + lm, g, A[rt][0], A[rt][1]);
    const short* bp = (const short*)Bp0;
    const short8v B0 = *(const short8v*)&bp[((ct * 2 + 0) * 64 + l) * 8];
    const short8v B1 = *(const short8v*)&bp[((ct * 2 + 1) * 64 + l) * 8];
    const int col = ct * 16 + lm;
    const float bc = b[col];
#pragma unroll
    for (int rt = 0; rt < 2; rt++) {
        f32x4 a = {0.f, 0.f, 0.f, 0.f};
        a = __builtin_amdgcn_mfma_f32_16x16x32_bf16(A[rt][0], B0, a, 0, 0, 0);
        a = __builtin_amdgcn_mfma_f32_16x16x32_bf16(A[rt][1], B1, a, 0, 0, 0);
#pragma unroll
        for (int reg = 0; reg < 4; reg++) {
            const int rowg = rowbase + rt * 16 + g * 4 + reg;
            xb[(size_t)rowg * 64 + col] = (unsigned short)f2bf(fmaxf(a[reg] + bc, 0.f));
        }
    }
}

// ---------------------------------------------------------------------------
__global__ __launch_bounds__(256) void k_scan1(const int* __restrict__ cnt,
                                               int* __restrict__ offs, int* __restrict__ bsum) {
    __shared__ int sm[256];
    const int t = threadIdx.x;
    const int i = blockIdx.x * 256 + t;
    const int v = (i < NN) ? cnt[i] : 0;
    sm[t] = v;
    __syncthreads();
    for (int off = 1; off < 256; off <<= 1) {
        const int x = (t >= off) ? sm[t - off] : 0;
        __syncthreads();
        sm[t] += x;
        __syncthreads();
    }
    if (i < NN) offs[i] = sm[t] - v;
    if (t == 255) bsum[blockIdx.x] = sm[255];
}

__global__ __launch_bounds__(512) void k_scan2(int* __restrict__ bsum) {
    __shared__ int sm[512];
    const int t = threadIdx.x;
    const int v = (t < NSB) ? bsum[t] : 0;
    sm[t] = v;
    __syncthreads();
    for (int off = 1; off < 512; off <<= 1) {
        const int x = (t >= off) ? sm[t - off] : 0;
        __syncthreads();
        sm[t] += x;
        __syncthreads();
    }
    if (t < NSB) bsum[t] = sm[t] - v;
}

__global__ __launch_bounds__(256) void k_scan3(int* __restrict__ offs,
                                               const int* __restrict__ bsum) {
    const int i = blockIdx.x * 256 + threadIdx.x;
    if (i < NN) offs[i] += bsum[blockIdx.x];
    if (i == 0) offs[NN] = NE;
}

// ---------------------------------------------------------------------------
// Fused, mod-7 interleaved: scatter (latency role) / MFMA proj layer 0.
__global__ __launch_bounds__(256) void k_scat_proj(const int* __restrict__ ei,
                                                   const float* __restrict__ eattr,
                                                   const float* __restrict__ sw,
                                                   const float* __restrict__ sb,
                                                   const int* __restrict__ rank,
                                                   const int* __restrict__ offs,
                                                   u32x2* __restrict__ meta,
                                                   const unsigned short* __restrict__ xb,
                                                   const unsigned short* __restrict__ Bp,
                                                   const float* __restrict__ bfv,
                                                   const float* __restrict__ bsv,
                                                   unsigned* __restrict__ Pd,
                                                   unsigned short* __restrict__ Ps8) {
    __shared__ __align__(16) short xl[32 * 64];
    const int r7 = blockIdx.x % 7;
    const int q7 = blockIdx.x / 7;
    if (r7 < 2) {
        __shared__ float swl[25], sbl[5];
        if (threadIdx.x < 25) swl[threadIdx.x] = sw[threadIdx.x];
        if (threadIdx.x >= 32 && threadIdx.x < 37) sbl[threadIdx.x - 32] = sb[threadIdx.x - 32];
        __syncthreads();
        const int base = (q7 * 2 + r7) * 1280 + threadIdx.x;
        int s[5], d[5], r[5];
        float ea[5][5];
#pragma unroll
        for (int j = 0; j < 5; j++) {
            const int e = base + j * 256;
            s[j] = ei[e];
            d[j] = ei[NE + e];
            r[j] = rank[e];
#pragma unroll
            for (int k = 0; k < 5; k++) ea[j][k] = eattr[(size_t)e * 5 + k];
        }
        int pos[5];
#pragma unroll
        for (int j = 0; j < 5; j++) pos[j] = offs[d[j]] + r[j];  // random load, no RMW
#pragma unroll
        for (int j = 0; j < 5; j++) {
            float e5[5];
#pragma unroll
            for (int k = 0; k < 5; k++) {
                float a = sbl[k];
#pragma unroll
                for (int q = 0; q < 5; q++) a += ea[j][q] * swl[q * 5 + k];
                e5[k] = fmaxf(a, 0.f);
            }
            unsigned hi = (unsigned)__builtin_amdgcn_cvt_pk_fp8_f32(e5[0], e5[1], 0, false);
            hi = (unsigned)__builtin_amdgcn_cvt_pk_fp8_f32(e5[2], e5[3], (int)hi, true);
            const unsigned b4 =
                (unsigned)__builtin_amdgcn_cvt_pk_fp8_f32(e5[4], 0.f, 0, false) & 0xFFu;
            u32x2 m;
            m.x = (unsigned)s[j] | (b4 << 24);
            m.y = hi;
            meta[pos[j]] = m;  // plain store: L2 write-combines within lines
        }
        return;
    }
    // ---- projm path (layer 0) ----
    const int rowbase = (q7 * 5 + (r7 - 2)) * 32;
    {
        const u32x4* xsrc = (const u32x4*)(xb + (size_t)rowbase * 64);
        const int i = threadIdx.x;
        const u32x4 v = __builtin_nontemporal_load(&xsrc[i]);
        *(u32x4*)&xl[swz(i >> 3, i & 7)] = v;
    }
    __syncthreads();
    const int ct = threadIdx.x >> 6;
    const int l = threadIdx.x & 63;
    const int lm = l & 15;
    const int g = l >> 4;
    short8v A[2][2];
#pragma unroll
    for (int rt = 0; rt < 2; rt++) frag_reads(xl, rt * 16 + lm, g, A[rt][0], A[rt][1]);
    const short* bp = (const short*)Bp;
    f32x4 acc[4][2];
#pragma unroll
    for (int m = 0; m < 4; m++) {
        const short8v B0 = *(const short8v*)&bp[(((m * 4 + ct) * 2 + 0) * 64 + l) * 8];
        const short8v B1 = *(const short8v*)&bp[(((m * 4 + ct) * 2 + 1) * 64 + l) * 8];
#pragma unroll
        for (int rt = 0; rt < 2; rt++) {
            f32x4 a = {0.f, 0.f, 0.f, 0.f};
            a = __builtin_amdgcn_mfma_f32_16x16x32_bf16(A[rt][0], B0, a, 0, 0, 0);
            a = __builtin_amdgcn_mfma_f32_16x16x32_bf16(A[rt][1], B1, a, 0, 0, 0);
            acc[m][rt] = a;
        }
    }
    const int col = ct * 16 + lm;
    const float bfb = -LOG2E * bfv[col];
    const float bsb = LOG2E * bsv[col];
#pragma unroll
    for (int rt = 0; rt < 2; rt++) {
#pragma unroll
        for (int reg = 0; reg < 4; reg++) {
            const int rowg = rowbase + rt * 16 + g * 4 + reg;
            Pd[(size_t)rowg * 64 + col] =
                f2bf(acc[0][rt][reg] + bfb) | (f2bf(acc[1][rt][reg] + bsb) << 16);
            Ps8[(size_t)rowg * 64 + col] = (unsigned short)__builtin_amdgcn_cvt_pk_fp8_f32(
                acc[2][rt][reg], acc[3][rt][reg], 0, false);
        }
    }
}

// ---------------------------------------------------------------------------
// MFMA projections (standalone, layer 1), 32 rows per block, swizzled LDS.
__global__ __launch_bounds__(256) void k_projm(const unsigned short* __restrict__ xb,
                                               const unsigned short* __restrict__ Bp,
                                               const float* __restrict__ bfv,
                                               const float* __restrict__ bsv,
                                               unsigned* __restrict__ Pd,
                                               unsigned short* __restrict__ Ps8) {
    __shared__ __align__(16) short xl[32 * 64];
    const int rowbase = blockIdx.x * 32;
    {
        const u32x4* xsrc = (const u32x4*)(xb + (size_t)rowbase * 64);
        const int i = threadIdx.x;
        const u32x4 v = __builtin_nontemporal_load(&xsrc[i]);
        *(u32x4*)&xl[swz(i >> 3, i & 7)] = v;
    }
    __syncthreads();
    const int ct = threadIdx.x >> 6;
    const int l = threadIdx.x & 63;
    const int lm = l & 15;
    const int g = l >> 4;
    short8v A[2][2];
#pragma unroll
    for (int rt = 0; rt < 2; rt++) frag_reads(xl, rt * 16 + lm, g, A[rt][0], A[rt][1]);
    const short* bp = (const short*)Bp;
    f32x4 acc[4][2];
#pragma unroll
    for (int m = 0; m < 4; m++) {
        const short8v B0 = *(const short8v*)&bp[(((m * 4 + ct) * 2 + 0) * 64 + l) * 8];
        const short8v B1 = *(const short8v*)&bp[(((m * 4 + ct) * 2 + 1) * 64 + l) * 8];
#pragma unroll
        for (int rt = 0; rt < 2; rt++) {
            f32x4 a = {0.f, 0.f, 0.f, 0.f};
            a = __builtin_amdgcn_mfma_f32_16x16x32_bf16(A[rt][0], B0, a, 0, 0, 0);
            a = __builtin_amdgcn_mfma_f32_16x16x32_bf16(A[rt][1], B1, a, 0, 0, 0);
            acc[m][rt] = a;
        }
    }
    const int col = ct * 16 + lm;
    const float bfb = -LOG2E * bfv[col];
    const float bsb = LOG2E * bsv[col];
#pragma unroll
    for (int rt = 0; rt < 2; rt++) {
#pragma unroll
        for (int reg = 0; reg < 4; reg++) {
            const int rowg = rowbase + rt * 16 + g * 4 + reg;
            Pd[(size_t)rowg * 64 + col] =
                f2bf(acc[0][rt][reg] + bfb) | (f2bf(acc[1][rt][reg] + bsb) << 16);
            Ps8[(size_t)rowg * 64 + col] = (unsigned short)__builtin_amdgcn_cvt_pk_fp8_f32(
                acc[2][rt][reg], acc[3][rt][reg], 0, false);
        }
    }
}

// ---------------------------------------------------------------------------
// Segment aggregation: ONE WAVE = ONE BLOCK = ONE NODE (64-thread blocks).
// Depth-2 pipeline (meta 2 batches ahead scalar, Ps 1 ahead), 8B fp8 meta,
// pre-packed W2 edge-weight table (5 dwordx2 loads, no per-node muls).
__global__ __launch_bounds__(64) void k_seg(const int* __restrict__ offs,
                                            const u32x2* __restrict__ meta,
                                            const unsigned* __restrict__ Pd,
                                            const unsigned short* __restrict__ Ps8,
                                            const f32x2* __restrict__ W2L,
                                            const unsigned short* __restrict__ xbin,
                                            float* __restrict__ outf,
                                            unsigned short* __restrict__ xbout) {
    const int n = blockIdx.x;
    const int lane = threadIdx.x;
    const int start = __builtin_amdgcn_readfirstlane(offs[n]);
    const int end = __builtin_amdgcn_readfirstlane(offs[n + 1]);
    const unsigned pd = __builtin_nontemporal_load(&Pd[(size_t)n * 64 + lane]);
    f32x2 pd2;
    pd2.x = bflo(pd);
    pd2.y = __uint_as_float(pd & 0xFFFF0000u);
    f32x2 w2[5];
#pragma unroll
    for (int k = 0; k < 5; k++) w2[k] = W2L[k * 64 + lane];
    const float xv = bflo((unsigned)xbin[(size_t)n * 64 + lane]);
    float acc0 = 0.f, acc1 = 0.f;
    const int cnt = end - start;
    if (cnt > 0) {
        const int last = end - 1;
        const int nbF = (cnt + 3) >> 2;
        u32x2 M0[4], M1[4];
        unsigned PS0[4];
#pragma unroll
        for (int j = 0; j < 4; j++) M0[j] = meta[imin(start + j, last)];
#pragma unroll
        for (int j = 0; j < 4; j++) M1[j] = meta[imin(start + 4 + j, last)];
#pragma unroll
        for (int j = 0; j < 4; j++) PS0[j] = Ps8[(size_t)(M0[j].x & 0xFFFFFFu) * 64 + lane];
        for (int b = 0; b < nbF - 1; b++) {
            const int base2 = __builtin_amdgcn_readfirstlane(start + (b + 2) * 4);
            u32x2 M2[4];
            unsigned PS1[4];
#pragma unroll
            for (int j = 0; j < 4; j++) M2[j] = meta[imin(base2 + j, last)];
#pragma unroll
            for (int j = 0; j < 4; j++) PS1[j] = Ps8[(size_t)(M1[j].x & 0xFFFFFFu) * 64 + lane];
            acc0 = edge_acc(M0[0], PS0[0], pd2, w2, acc0);
            acc1 = edge_acc(M0[1], PS0[1], pd2, w2, acc1);
            acc0 = edge_acc(M0[2], PS0[2], pd2, w2, acc0);
            acc1 = edge_acc(M0[3], PS0[3], pd2, w2, acc1);
#pragma unroll
            for (int j = 0; j < 4; j++) {
                M0[j] = M1[j];
                M1[j] = M2[j];
                PS0[j] = PS1[j];
            }
        }
        const int lb = start + (nbF - 1) * 4;
        if (lb + 0 < end) acc0 = edge_acc(M0[0], PS0[0], pd2, w2, acc0);
        if (lb + 1 < end) acc1 = edge_acc(M0[1], PS0[1], pd2, w2, acc1);
        if (lb + 2 < end) acc0 = edge_acc(M0[2], PS0[2], pd2, w2, acc0);
        if (lb + 3 < end) acc1 = edge_acc(M0[3], PS0[3], pd2, w2, acc1);
    }
    const float res = fmaxf(fmaf(acc0 + acc1, LN2, xv), 0.f);
    if (outf) {
        __builtin_nontemporal_store(res, &outf[(size_t)n * 64 + lane]);  // final f32
    } else {
        xbout[(size_t)n * 64 + lane] = (unsigned short)f2bf(res);  // XB in-place
    }
}

// ---------------------------------------------------------------------------
extern "C" void kernel_launch(void* const* d_in, const int* in_sizes, int n_in,
                              void* d_out, int out_size, void* d_ws, size_t ws_size,
                              hipStream_t stream) {
    const float* h = (const float*)d_in[0];
    const int* ei = (const int*)d_in[1];
    const float* eattr = (const float*)d_in[3];
    const float* lin0_w = (const float*)d_in[5];
    const float* lin0_b = (const float*)d_in[6];
    const float* short_w = (const float*)d_in[7];
    const float* short_b = (const float*)d_in[8];
    const float* conv_f_w = (const float*)d_in[9];
    const float* conv_f_b = (const float*)d_in[10];
    const float* conv_s_w = (const float*)d_in[11];
    const float* conv_s_b = (const float*)d_in[12];

    char* ws = (char*)d_ws;
    u32x2* meta = (u32x2*)ws;                             // [NE] 8B, 12.8 MB
    unsigned* Pd = (unsigned*)(ws + (size_t)NE * 8);      // [NN*64] u32 (bf16 pair)
    unsigned short* Ps8 = (unsigned short*)(Pd + (size_t)NN * 64);  // [NN*64] u16 (fp8 pair)
    unsigned short* XB = Ps8 + (size_t)NN * 64;           // [NN*64] bf16 node features
    unsigned short* Bp = XB + (size_t)NN * 64;            // [2][16384]+[4096] packed weights
    f32x2* W2 = (f32x2*)(Bp + 36864);                     // [2][320] edge-weight pairs
    int* cnt = (int*)(W2 + 640);                          // [NN]
    int* offs = cnt + NN;                                 // [NN+1]
    int* bsum = offs + NN + 1;                            // [NSB]
    int* rank = bsum + NSB;                               // [NE]

    hipMemsetAsync(cnt, 0, (size_t)NN * 4, stream);
    k_wpack<<<21, 256, 0, stream>>>(conv_f_w, conv_s_w, lin0_w, Bp, W2);
    k_lin0m_hist<<<4375, 256, 0, stream>>>(h, Bp + 32768, lin0_b, XB, ei, cnt, rank);
    k_scan1<<<NSB, 256, 0, stream>>>(cnt, offs, bsum);
    k_scan2<<<1, 512, 0, stream>>>(bsum);
    k_scan3<<<NSB, 256, 0, stream>>>(offs, bsum);
    // layer 0: scatter fused with projm (mod-7 interleaved, overlapped)
    k_scat_proj<<<4375, 256, 0, stream>>>(ei, eattr, short_w, short_b, rank, offs,
                                          meta, XB, Bp, conv_f_b, conv_s_b, Pd, Ps8);
    k_seg<<<NN, 64, 0, stream>>>(offs, meta, Pd, Ps8, W2, XB, nullptr, XB);
    // layer 1
    k_projm<<<NN / 32, 256, 0, stream>>>(XB, Bp + 16384, conv_f_b + 64, conv_s_b + 64, Pd, Ps8);
    k_seg<<<NN, 64, 0, stream>>>(offs, meta, Pd, Ps8, W2 + 320, XB, (float*)d_out, nullptr);
}